// Round 1
// baseline (314.505 us; speedup 1.0000x reference)
//
#include <hip/hip_runtime.h>
#include <hip/hip_bf16.h>
#include <math.h>

typedef __bf16 bf16_t;
typedef bf16_t bf16x8 __attribute__((ext_vector_type(8)));
typedef float f32x4 __attribute__((ext_vector_type(4)));
typedef unsigned short u16;
typedef unsigned int u32;

#define AS1 __attribute__((address_space(1)))
#define AS3 __attribute__((address_space(3)))

static __device__ __forceinline__ void gll16(const void* g, void* l){
  __builtin_amdgcn_global_load_lds((const AS1 u32*)g, (AS3 u32*)l, 16, 0, 0);
}

static __device__ __forceinline__ u16 f2bf(float f){
  u32 u = __builtin_bit_cast(u32, f);
  u = u + 0x7FFFu + ((u >> 16) & 1u);
  return (u16)(u >> 16);
}

// ---------------- prep: cast hidden fp32 -> bf16 ----------------
__global__ void k_cast_hidden(const float* __restrict__ h, u16* __restrict__ hb, int n4){
  int i = blockIdx.x * blockDim.x + threadIdx.x;
  int stride = gridDim.x * blockDim.x;
  for (; i < n4; i += stride){
    float4 v = ((const float4*)h)[i];
    ushort4 o;
    o.x = f2bf(v.x); o.y = f2bf(v.y); o.z = f2bf(v.z); o.w = f2bf(v.w);
    ((ushort4*)hb)[i] = o;
  }
}

// ---------------- prep: W^T concat (bf16), bias concat, inv_freq ----------------
__global__ void k_prep_w(const float* __restrict__ Wq, const float* __restrict__ Wk,
                         const float* __restrict__ Wv, const float* __restrict__ bq,
                         const float* __restrict__ bk, const float* __restrict__ bv,
                         u16* __restrict__ wt, float* __restrict__ bc, float* __restrict__ invf){
  int i = blockIdx.x * blockDim.x + threadIdx.x;
  int stride = gridDim.x * blockDim.x;
  for (int idx = i; idx < 1536 * 512; idx += stride){
    int j = idx >> 9, k = idx & 511;          // wt[j][k] = W[k][j']
    int t = j >> 9, jj = j & 511;
    const float* W = (t == 0) ? Wq : (t == 1 ? Wk : Wv);
    wt[idx] = f2bf(W[k * 512 + jj]);
  }
  if (i < 1536){
    int t = i >> 9, jj = i & 511;
    const float* bsrc = (t == 0) ? bq : (t == 1 ? bk : bv);
    bc[i] = bsrc[jj];
  }
  if (i < 32){
    invf[i] = 1.0f / (float)pow(10000.0, (double)(2 * i) / 64.0);
  }
}

// ---------------- fused QKV GEMM + bias + RoPE + layout ----------------
// out: q,k as [slice=b*8+h][4096][64] bf16 (q pre-scaled by 0.125), v as [slice][64][4096] bf16 (transposed)
__global__ __launch_bounds__(256) void k_proj(const u16* __restrict__ hb, const u16* __restrict__ wt,
                      const float* __restrict__ bc, const float* __restrict__ invf,
                      u16* __restrict__ qws, u16* __restrict__ kws, u16* __restrict__ vt){
  __shared__ __align__(16) u16 At[128 * 64];
  __shared__ __align__(16) u16 Bt[128 * 64];
  int tid = threadIdx.x;
  int lane = tid & 63;
  int c = lane & 15, g = lane >> 4;
  int wave = tid >> 6;
  int wm = wave >> 1, wn = wave & 1;
  int m0 = blockIdx.x * 128;
  int n0 = blockIdx.y * 128;

  const f32x4 vzero = {0.f, 0.f, 0.f, 0.f};
  f32x4 acc[4][4];
#pragma unroll
  for (int a = 0; a < 4; ++a)
#pragma unroll
    for (int b2 = 0; b2 < 4; ++b2) acc[a][b2] = vzero;

  for (int kc = 0; kc < 512; kc += 64){
    __syncthreads();
#pragma unroll
    for (int it = 0; it < 4; ++it){
      int j16 = it * 256 + tid;               // 1024 16B-units per tile
      int row = j16 >> 3, u = j16 & 7;
      int us = u ^ (row & 7);                 // pre-swizzled global source
      gll16(hb + (size_t)(m0 + row) * 512 + kc + us * 8, &At[j16 * 8]);
      gll16(wt + (size_t)(n0 + row) * 512 + kc + us * 8, &Bt[j16 * 8]);
    }
    __syncthreads();
#pragma unroll
    for (int ch = 0; ch < 2; ++ch){
      bf16x8 af[4], bfg[4];
#pragma unroll
      for (int mt = 0; mt < 4; ++mt){
        int r = wm * 64 + mt * 16 + c;
        af[mt] = *(const bf16x8*)&At[r * 64 + ((g + 4 * ch) ^ (r & 7)) * 8];
      }
#pragma unroll
      for (int nt = 0; nt < 4; ++nt){
        int r = wn * 64 + nt * 16 + c;
        bfg[nt] = *(const bf16x8*)&Bt[r * 64 + ((g + 4 * ch) ^ (r & 7)) * 8];
      }
#pragma unroll
      for (int mt = 0; mt < 4; ++mt)
#pragma unroll
        for (int nt = 0; nt < 4; ++nt)
          acc[mt][nt] = __builtin_amdgcn_mfma_f32_16x16x32_bf16(af[mt], bfg[nt], acc[mt][nt], 0, 0, 0);
    }
  }

  int colbase = n0 + wn * 64;                 // multiple of 64 -> single (type, head)
  int typ = colbase >> 9;                     // 0=q 1=k 2=v
  int head = (colbase >> 6) & 7;
  float bias[4], fi[4];
#pragma unroll
  for (int nt = 0; nt < 4; ++nt){
    bias[nt] = bc[colbase + nt * 16 + c];
    fi[nt] = invf[(nt * 16 + c) >> 1];
  }
  int rowbase = m0 + wm * 64;
#pragma unroll
  for (int mt = 0; mt < 4; ++mt){
#pragma unroll
    for (int reg = 0; reg < 4; ++reg){
      int m = rowbase + mt * 16 + g * 4 + reg;
      int b = m >> 12, s = m & 4095;
      float y[4];
#pragma unroll
      for (int nt = 0; nt < 4; ++nt) y[nt] = acc[mt][nt][reg] + bias[nt];
      if (typ == 2){
        size_t base = (size_t)(b * 8 + head) * 64 * 4096 + s;
#pragma unroll
        for (int nt = 0; nt < 4; ++nt)
          vt[base + (size_t)(nt * 16 + c) * 4096] = f2bf(y[nt]);
      } else {
        float sp = (float)s;
        u16* dst = (typ == 0) ? qws : kws;
        size_t base = ((size_t)(b * 8 + head) * 4096 + s) * 64;
        float scale = (typ == 0) ? 0.125f : 1.0f;   // fold 1/sqrt(64) into q
#pragma unroll
        for (int nt = 0; nt < 4; ++nt){
          float ang = sp * fi[nt];
          float cv, sn;
          sincosf(ang, &sn, &cv);
          float rot = (nt < 2) ? -y[nt + 2] : y[nt - 2];
          float o = (y[nt] * cv + rot * sn) * scale;
          dst[base + nt * 16 + c] = f2bf(o);
        }
      }
    }
  }
}

// ---------------- flash attention ----------------
__global__ __launch_bounds__(256) void k_attn(const u16* __restrict__ qws, const u16* __restrict__ kws,
                      const u16* __restrict__ vtws, const float* __restrict__ mask,
                      float* __restrict__ out){
  __shared__ __align__(16) u16 Kb[64 * 64];        // [key][d], swizzled
  __shared__ __align__(16) u16 Vt[64 * 64];        // [d][key], swizzled
  __shared__ __align__(16) u16 Pl[4][16 * 72];     // per-wave P, 144B row stride

  int tid = threadIdx.x;
  int lane = tid & 63;
  int c = lane & 15, g = lane >> 4;
  int wave = tid >> 6;
  int slice = blockIdx.y;                           // b*8+h
  int b = slice >> 3;
  int q0 = blockIdx.x * 64 + wave * 16;

  const u16* qs = qws + (size_t)slice * 4096 * 64;
  const u16* ks = kws + (size_t)slice * 4096 * 64;
  const u16* vs = vtws + (size_t)slice * 64 * 4096;
  const float* mk = mask + b * 4096;

  const f32x4 vzero = {0.f, 0.f, 0.f, 0.f};
  bf16x8 qf[2];
#pragma unroll
  for (int h2 = 0; h2 < 2; ++h2)
    qf[h2] = *(const bf16x8*)&qs[(size_t)(q0 + c) * 64 + g * 8 + h2 * 32];

  f32x4 ctx[4];
#pragma unroll
  for (int dt = 0; dt < 4; ++dt) ctx[dt] = vzero;
  float mrow[4] = {-1e30f, -1e30f, -1e30f, -1e30f};
  float lrow[4] = {0.f, 0.f, 0.f, 0.f};
  u16* Pw = &Pl[wave][0];

  for (int kc = 0; kc < 4096; kc += 64){
    __syncthreads();
#pragma unroll
    for (int it = 0; it < 2; ++it){
      int j16 = it * 256 + tid;                    // 512 units per buffer
      int row = j16 >> 3, u = j16 & 7;
      int us = u ^ (row & 7);
      gll16(ks + (size_t)(kc + row) * 64 + us * 8, &Kb[j16 * 8]);
      gll16(vs + (size_t)row * 4096 + kc + us * 8, &Vt[j16 * 8]);
    }
    __syncthreads();

    float mv[4];
#pragma unroll
    for (int ct = 0; ct < 4; ++ct) mv[ct] = mk[kc + ct * 16 + c];

    float sv[4][4];                                // [ct][reg]
#pragma unroll
    for (int ct = 0; ct < 4; ++ct){
      f32x4 facc = vzero;
#pragma unroll
      for (int h2 = 0; h2 < 2; ++h2){
        int r = ct * 16 + c;
        bf16x8 kb = *(const bf16x8*)&Kb[r * 64 + ((g + 4 * h2) ^ (r & 7)) * 8];
        facc = __builtin_amdgcn_mfma_f32_16x16x32_bf16(qf[h2], kb, facc, 0, 0, 0);
      }
#pragma unroll
      for (int reg = 0; reg < 4; ++reg) sv[ct][reg] = facc[reg] + mv[ct];
    }

    float tmax[4], al[4], rs[4], p[4][4];
#pragma unroll
    for (int reg = 0; reg < 4; ++reg)
      tmax[reg] = fmaxf(fmaxf(sv[0][reg], sv[1][reg]), fmaxf(sv[2][reg], sv[3][reg]));
#pragma unroll
    for (int off = 8; off >= 1; off >>= 1)
#pragma unroll
      for (int reg = 0; reg < 4; ++reg)
        tmax[reg] = fmaxf(tmax[reg], __shfl_xor(tmax[reg], off));
#pragma unroll
    for (int reg = 0; reg < 4; ++reg){
      float mn = fmaxf(mrow[reg], tmax[reg]);
      al[reg] = __expf(mrow[reg] - mn);
      mrow[reg] = mn;
      rs[reg] = 0.f;
    }
#pragma unroll
    for (int ct = 0; ct < 4; ++ct)
#pragma unroll
      for (int reg = 0; reg < 4; ++reg){
        p[ct][reg] = __expf(sv[ct][reg] - mrow[reg]);
        rs[reg] += p[ct][reg];
      }
#pragma unroll
    for (int off = 8; off >= 1; off >>= 1)
#pragma unroll
      for (int reg = 0; reg < 4; ++reg)
        rs[reg] += __shfl_xor(rs[reg], off);
#pragma unroll
    for (int reg = 0; reg < 4; ++reg)
      lrow[reg] = lrow[reg] * al[reg] + rs[reg];
#pragma unroll
    for (int dt = 0; dt < 4; ++dt)
#pragma unroll
      for (int reg = 0; reg < 4; ++reg)
        ctx[dt][reg] *= al[reg];

    // P -> per-wave LDS (D-layout scatter), then read back as A-frags
#pragma unroll
    for (int ct = 0; ct < 4; ++ct)
#pragma unroll
      for (int reg = 0; reg < 4; ++reg)
        Pw[(g * 4 + reg) * 72 + ct * 16 + c] = f2bf(p[ct][reg]);

    bf16x8 pa[2];
#pragma unroll
    for (int h2 = 0; h2 < 2; ++h2)
      pa[h2] = *(const bf16x8*)&Pw[c * 72 + (g + 4 * h2) * 8];

#pragma unroll
    for (int dt = 0; dt < 4; ++dt){
#pragma unroll
      for (int h2 = 0; h2 < 2; ++h2){
        int r = dt * 16 + c;
        bf16x8 vb = *(const bf16x8*)&Vt[r * 64 + ((g + 4 * h2) ^ (r & 7)) * 8];
        ctx[dt] = __builtin_amdgcn_mfma_f32_16x16x32_bf16(pa[h2], vb, ctx[dt], 0, 0, 0);
      }
    }
  }

  float inv[4];
#pragma unroll
  for (int reg = 0; reg < 4; ++reg) inv[reg] = 1.0f / lrow[reg];
#pragma unroll
  for (int dt = 0; dt < 4; ++dt)
#pragma unroll
    for (int reg = 0; reg < 4; ++reg){
      int s = q0 + g * 4 + reg;
      int hcol = (slice & 7) * 64 + dt * 16 + c;
      out[(size_t)(b * 4096 + s) * 512 + hcol] = ctx[dt][reg] * inv[reg];
    }
}

extern "C" void kernel_launch(void* const* d_in, const int* in_sizes, int n_in,
                              void* d_out, int out_size, void* d_ws, size_t ws_size,
                              hipStream_t stream) {
  const float* hidden = (const float*)d_in[0];
  const float* mask   = (const float*)d_in[1];
  const float* Wq = (const float*)d_in[2];
  const float* bq = (const float*)d_in[3];
  const float* Wk = (const float*)d_in[4];
  const float* bk = (const float*)d_in[5];
  const float* Wv = (const float*)d_in[6];
  const float* bv = (const float*)d_in[7];
  float* out = (float*)d_out;
  char* ws = (char*)d_ws;

  u16* hb    = (u16*)(ws + 0x00000000);   // 8192x512 bf16      (8.0 MiB)
  u16* wt    = (u16*)(ws + 0x00900000);   // 1536x512 bf16      (1.5 MiB)
  float* bc  = (float*)(ws + 0x00B00000); // 1536 f32
  float* invf= (float*)(ws + 0x00B02000); // 32 f32
  u16* qws   = (u16*)(ws + 0x00C00000);   // 16x4096x64 bf16    (8 MiB)
  u16* kws   = (u16*)(ws + 0x01400000);   // 16x4096x64 bf16
  u16* vtws  = (u16*)(ws + 0x01C00000);   // 16x64x4096 bf16

  k_cast_hidden<<<dim3(2048), dim3(256), 0, stream>>>(hidden, hb, (2 * 4096 * 512) / 4);
  k_prep_w<<<dim3(1024), dim3(256), 0, stream>>>(Wq, Wk, Wv, bq, bk, bv, wt, bc, invf);
  k_proj<<<dim3(64, 12), dim3(256), 0, stream>>>(hb, wt, bc, invf, qws, kws, vtws);
  k_attn<<<dim3(64, 16), dim3(256), 0, stream>>>(qws, kws, vtws, mask, out);
}

// Round 2
// 218.915 us; speedup vs baseline: 1.4367x; 1.4367x over previous
//
#include <hip/hip_runtime.h>
#include <hip/hip_bf16.h>
#include <math.h>

typedef __bf16 bf16_t;
typedef bf16_t bf16x8 __attribute__((ext_vector_type(8)));
typedef bf16_t bf16x2 __attribute__((ext_vector_type(2)));
typedef float f32x2 __attribute__((ext_vector_type(2)));
typedef float f32x4 __attribute__((ext_vector_type(4)));
typedef float f32x16 __attribute__((ext_vector_type(16)));
typedef unsigned short u16;
typedef unsigned int u32;
typedef u32 u32x4 __attribute__((ext_vector_type(4)));

#define AS1 __attribute__((address_space(1)))
#define AS3 __attribute__((address_space(3)))

static __device__ __forceinline__ void gll16(const void* g, void* l){
  __builtin_amdgcn_global_load_lds((const AS1 u32*)g, (AS3 u32*)l, 16, 0, 0);
}

static __device__ __forceinline__ u16 f2bf(float f){
  u32 u = __builtin_bit_cast(u32, f);
  u = u + 0x7FFFu + ((u >> 16) & 1u);
  return (u16)(u >> 16);
}

static __device__ __forceinline__ u32 pk2(float a, float b){
  f32x2 v = {a, b};
  bf16x2 w = __builtin_convertvector(v, bf16x2);
  return __builtin_bit_cast(u32, w);
}

// exchange halves: returns (w0, w2) pair semantics — a' = own-low/partner-low, b' = partner-high/own-high
static __device__ __forceinline__ void swap32(u32& a, u32& b, int hi){
#if __has_builtin(__builtin_amdgcn_permlane32_swap)
  auto r = __builtin_amdgcn_permlane32_swap((int)a, (int)b, false, false);
  a = (u32)r[0];
  b = (u32)r[1];
#else
  u32 xa = (u32)__shfl_xor((int)a, 32);
  u32 xb = (u32)__shfl_xor((int)b, 32);
  u32 na = hi ? xb : a;
  u32 nb = hi ? b : xa;
  a = na; b = nb;
#endif
}

// ---------------- prep: cast hidden fp32 -> bf16 ----------------
__global__ void k_cast_hidden(const float* __restrict__ h, u16* __restrict__ hb, int n4){
  int i = blockIdx.x * blockDim.x + threadIdx.x;
  int stride = gridDim.x * blockDim.x;
  for (; i < n4; i += stride){
    float4 v = ((const float4*)h)[i];
    ushort4 o;
    o.x = f2bf(v.x); o.y = f2bf(v.y); o.z = f2bf(v.z); o.w = f2bf(v.w);
    ((ushort4*)hb)[i] = o;
  }
}

// ---------------- prep: W^T concat (bf16), bias concat, inv_freq ----------------
__global__ void k_prep_w(const float* __restrict__ Wq, const float* __restrict__ Wk,
                         const float* __restrict__ Wv, const float* __restrict__ bq,
                         const float* __restrict__ bk, const float* __restrict__ bv,
                         u16* __restrict__ wt, float* __restrict__ bc, float* __restrict__ invf){
  int i = blockIdx.x * blockDim.x + threadIdx.x;
  int stride = gridDim.x * blockDim.x;
  for (int idx = i; idx < 1536 * 512; idx += stride){
    int j = idx >> 9, k = idx & 511;          // wt[j][k] = W[k][j']
    int t = j >> 9, jj = j & 511;
    const float* W = (t == 0) ? Wq : (t == 1 ? Wk : Wv);
    wt[idx] = f2bf(W[k * 512 + jj]);
  }
  if (i < 1536){
    int t = i >> 9, jj = i & 511;
    const float* bsrc = (t == 0) ? bq : (t == 1 ? bk : bv);
    bc[i] = bsrc[jj];
  }
  if (i < 32){
    invf[i] = 1.0f / (float)pow(10000.0, (double)(2 * i) / 64.0);
  }
}

// ---------------- fused QKV GEMM + bias + RoPE + layout ----------------
// out: q,k as [slice=b*8+h][4096][64] bf16 (q pre-scaled by 0.125), v as [slice][64][4096] bf16 (transposed)
__global__ __launch_bounds__(256) void k_proj(const u16* __restrict__ hb, const u16* __restrict__ wt,
                      const float* __restrict__ bc, const float* __restrict__ invf,
                      u16* __restrict__ qws, u16* __restrict__ kws, u16* __restrict__ vt){
  __shared__ __align__(16) u16 At[128 * 64];
  __shared__ __align__(16) u16 Bt[128 * 64];
  int tid = threadIdx.x;
  int lane = tid & 63;
  int c = lane & 15, g = lane >> 4;
  int wave = tid >> 6;
  int wm = wave >> 1, wn = wave & 1;
  int m0 = blockIdx.x * 128;
  int n0 = blockIdx.y * 128;

  const f32x4 vzero = {0.f, 0.f, 0.f, 0.f};
  f32x4 acc[4][4];
#pragma unroll
  for (int a = 0; a < 4; ++a)
#pragma unroll
    for (int b2 = 0; b2 < 4; ++b2) acc[a][b2] = vzero;

  for (int kc = 0; kc < 512; kc += 64){
    __syncthreads();
#pragma unroll
    for (int it = 0; it < 4; ++it){
      int j16 = it * 256 + tid;               // 1024 16B-units per tile
      int row = j16 >> 3, u = j16 & 7;
      int us = u ^ (row & 7);                 // pre-swizzled global source
      gll16(hb + (size_t)(m0 + row) * 512 + kc + us * 8, &At[j16 * 8]);
      gll16(wt + (size_t)(n0 + row) * 512 + kc + us * 8, &Bt[j16 * 8]);
    }
    __syncthreads();
#pragma unroll
    for (int ch = 0; ch < 2; ++ch){
      bf16x8 af[4], bfg[4];
#pragma unroll
      for (int mt = 0; mt < 4; ++mt){
        int r = wm * 64 + mt * 16 + c;
        af[mt] = *(const bf16x8*)&At[r * 64 + ((g + 4 * ch) ^ (r & 7)) * 8];
      }
#pragma unroll
      for (int nt = 0; nt < 4; ++nt){
        int r = wn * 64 + nt * 16 + c;
        bfg[nt] = *(const bf16x8*)&Bt[r * 64 + ((g + 4 * ch) ^ (r & 7)) * 8];
      }
#pragma unroll
      for (int mt = 0; mt < 4; ++mt)
#pragma unroll
        for (int nt = 0; nt < 4; ++nt)
          acc[mt][nt] = __builtin_amdgcn_mfma_f32_16x16x32_bf16(af[mt], bfg[nt], acc[mt][nt], 0, 0, 0);
    }
  }

  int colbase = n0 + wn * 64;                 // multiple of 64 -> single (type, head)
  int typ = colbase >> 9;                     // 0=q 1=k 2=v
  int head = (colbase >> 6) & 7;
  float bias[4], fi[4];
#pragma unroll
  for (int nt = 0; nt < 4; ++nt){
    bias[nt] = bc[colbase + nt * 16 + c];
    fi[nt] = invf[(nt * 16 + c) >> 1];
  }
  int rowbase = m0 + wm * 64;
#pragma unroll
  for (int mt = 0; mt < 4; ++mt){
#pragma unroll
    for (int reg = 0; reg < 4; ++reg){
      int m = rowbase + mt * 16 + g * 4 + reg;
      int b = m >> 12, s = m & 4095;
      float y[4];
#pragma unroll
      for (int nt = 0; nt < 4; ++nt) y[nt] = acc[mt][nt][reg] + bias[nt];
      if (typ == 2){
        size_t base = (size_t)(b * 8 + head) * 64 * 4096 + s;
#pragma unroll
        for (int nt = 0; nt < 4; ++nt)
          vt[base + (size_t)(nt * 16 + c) * 4096] = f2bf(y[nt]);
      } else {
        float sp = (float)s;
        u16* dst = (typ == 0) ? qws : kws;
        size_t base = ((size_t)(b * 8 + head) * 4096 + s) * 64;
        float scale = (typ == 0) ? 0.125f : 1.0f;   // fold 1/sqrt(64) into q
#pragma unroll
        for (int nt = 0; nt < 4; ++nt){
          float ang = sp * fi[nt];
          float cv, sn;
          sincosf(ang, &sn, &cv);
          float rot = (nt < 2) ? -y[nt + 2] : y[nt - 2];
          float o = (y[nt] * cv + rot * sn) * scale;
          dst[base + nt * 16 + c] = f2bf(o);
        }
      }
    }
  }
}

// ---------------- flash attention: 4 waves x 32q, 32x32x16 MFMA, in-register softmax ----------------
__global__ __launch_bounds__(256) void k_attn(const u16* __restrict__ qws, const u16* __restrict__ kws,
                      const u16* __restrict__ vtws, const float* __restrict__ mask,
                      float* __restrict__ out){
  __shared__ __align__(16) u16 smem[2][2][64 * 64];  // [buf][K=0/Vt=1][row*64+d], XOR-swizzled 16B units

  int tid = threadIdx.x;
  int lane = tid & 63;
  int q = lane & 31, hi = lane >> 5;
  int wave = tid >> 6;

  // XCD-aware bijective swizzle: 512 blocks, 8 XCDs -> 2 slices per XCD (K/V L2-resident)
  int nbid = (blockIdx.x & 7) * 64 + (blockIdx.x >> 3);
  int slice = nbid >> 5;                            // b*8+h
  int qt = nbid & 31;
  int b = slice >> 3, head = slice & 7;
  int q0 = qt * 128 + wave * 32;

  const u16* qs = qws + (size_t)slice * 4096 * 64;
  const u16* ks = kws + (size_t)slice * 4096 * 64;
  const u16* vs = vtws + (size_t)slice * 64 * 4096;
  const float* mk = mask + b * 4096;

  // Q fragments: B-operand, lane holds Q[q][d = dblk*16 + hi*8 + e], pre-scaled by 1/8
  const u16* qrow = qs + (size_t)(q0 + q) * 64;
  bf16x8 qf[4];
#pragma unroll
  for (int dblk = 0; dblk < 4; ++dblk)
    qf[dblk] = *(const bf16x8*)&qrow[dblk * 16 + hi * 8];

  const f32x16 vz = {0.f,0.f,0.f,0.f,0.f,0.f,0.f,0.f,0.f,0.f,0.f,0.f,0.f,0.f,0.f,0.f};
  f32x16 ctx0 = vz, ctx1 = vz;
  float m_run = -1e30f, l_run = 0.f;

  auto stage = [&](int buf, int kc){
#pragma unroll
    for (int it = 0; it < 2; ++it){
      int j = it * 256 + tid;                      // 512 16B-units per tile
      int row = j >> 3, u = j & 7;
      int us = u ^ (row & 7);
      gll16(ks + (size_t)(kc + row) * 64 + us * 8, &smem[buf][0][j * 8]);
      gll16(vs + (size_t)row * 4096 + kc + us * 8, &smem[buf][1][j * 8]);
    }
  };

  stage(0, 0);

  for (int t = 0; t < 64; ++t){
    __syncthreads();                               // drains vmcnt -> buf[t&1] ready
    if (t < 63) stage((t + 1) & 1, (t + 1) * 64);  // prefetch overlaps with compute below
    const u16* Kb  = &smem[t & 1][0][0];
    const u16* Vtc = &smem[t & 1][1][0];
    int kc = t * 64;

    // QK^T (swapped): S^T[key][q], acc reg -> key = (reg&3)+8*(reg>>2)+4*hi (+32*kb)
    f32x16 sv[2];
#pragma unroll
    for (int kb = 0; kb < 2; ++kb){
      f32x16 acc = vz;
#pragma unroll
      for (int dblk = 0; dblk < 4; ++dblk){
        int row = kb * 32 + q;
        bf16x8 kf = *(const bf16x8*)&Kb[row * 64 + (((dblk * 2 + hi) ^ (row & 7)) * 8)];
        acc = __builtin_amdgcn_mfma_f32_32x32x16_bf16(kf, qf[dblk], acc, 0, 0, 0);
      }
      // add attention mask (per key, uniform over q)
#pragma unroll
      for (int gg = 0; gg < 4; ++gg){
        float4 m4 = *(const float4*)&mk[kc + kb * 32 + gg * 8 + hi * 4];
        acc[4 * gg + 0] += m4.x;
        acc[4 * gg + 1] += m4.y;
        acc[4 * gg + 2] += m4.z;
        acc[4 * gg + 3] += m4.w;
      }
      sv[kb] = acc;
    }

    // online softmax: lane-local over 32 regs + one cross-half combine
    float mnew = m_run;
#pragma unroll
    for (int kb = 0; kb < 2; ++kb)
#pragma unroll
      for (int r = 0; r < 16; ++r) mnew = fmaxf(mnew, sv[kb][r]);
    mnew = fmaxf(mnew, __shfl_xor(mnew, 32));
    float al = __expf(m_run - mnew);
    m_run = mnew;
    float rs = 0.f;
#pragma unroll
    for (int kb = 0; kb < 2; ++kb)
#pragma unroll
      for (int r = 0; r < 16; ++r){
        float p = __expf(sv[kb][r] - mnew);
        sv[kb][r] = p;
        rs += p;
      }
    rs += __shfl_xor(rs, 32);
    l_run = l_run * al + rs;
#pragma unroll
    for (int r = 0; r < 16; ++r){ ctx0[r] *= al; ctx1[r] *= al; }

    // pack P to bf16 words: W0/W1[kb][g] cover regs 4g..4g+3
    u32 W0[2][4], W1[2][4];
#pragma unroll
    for (int kb = 0; kb < 2; ++kb)
#pragma unroll
      for (int g = 0; g < 4; ++g){
        W0[kb][g] = pk2(sv[kb][4 * g + 0], sv[kb][4 * g + 1]);
        W1[kb][g] = pk2(sv[kb][4 * g + 2], sv[kb][4 * g + 3]);
      }

    // assemble PV B-frags (P^T): lane needs keys 16*kblk + 8*hi + 0..7 for its q
    bf16x8 pb[4];
#pragma unroll
    for (int kblk = 0; kblk < 4; ++kblk){
      int kb = kblk >> 1, j = kblk & 1;
      u32 w0 = W0[kb][2 * j + 0], w2 = W0[kb][2 * j + 1];
      u32 w1 = W1[kb][2 * j + 0], w3 = W1[kb][2 * j + 1];
      swap32(w0, w2, hi);
      swap32(w1, w3, hi);
      u32x4 wv = {w0, w1, w2, w3};
      pb[kblk] = __builtin_bit_cast(bf16x8, wv);
    }

    // PV: O^T[dv][q] += V^T[dv][key] * P^T[key][q]
#pragma unroll
    for (int kblk = 0; kblk < 4; ++kblk){
      int row0 = q;
      bf16x8 vf0 = *(const bf16x8*)&Vtc[row0 * 64 + (((kblk * 2 + hi) ^ (row0 & 7)) * 8)];
      ctx0 = __builtin_amdgcn_mfma_f32_32x32x16_bf16(vf0, pb[kblk], ctx0, 0, 0, 0);
      int row1 = 32 + q;
      bf16x8 vf1 = *(const bf16x8*)&Vtc[row1 * 64 + (((kblk * 2 + hi) ^ (row1 & 7)) * 8)];
      ctx1 = __builtin_amdgcn_mfma_f32_32x32x16_bf16(vf1, pb[kblk], ctx1, 0, 0, 0);
    }
  }

  // epilogue: O[q][dv] = ctx^T / l
  float invl = 1.0f / l_run;
  float* orow = out + (size_t)(b * 4096 + q0 + q) * 512 + head * 64;
#pragma unroll
  for (int g = 0; g < 4; ++g){
    float4 o0, o1;
    o0.x = ctx0[4 * g + 0] * invl; o0.y = ctx0[4 * g + 1] * invl;
    o0.z = ctx0[4 * g + 2] * invl; o0.w = ctx0[4 * g + 3] * invl;
    *(float4*)&orow[8 * g + 4 * hi] = o0;
    o1.x = ctx1[4 * g + 0] * invl; o1.y = ctx1[4 * g + 1] * invl;
    o1.z = ctx1[4 * g + 2] * invl; o1.w = ctx1[4 * g + 3] * invl;
    *(float4*)&orow[32 + 8 * g + 4 * hi] = o1;
  }
}

extern "C" void kernel_launch(void* const* d_in, const int* in_sizes, int n_in,
                              void* d_out, int out_size, void* d_ws, size_t ws_size,
                              hipStream_t stream) {
  const float* hidden = (const float*)d_in[0];
  const float* mask   = (const float*)d_in[1];
  const float* Wq = (const float*)d_in[2];
  const float* bq = (const float*)d_in[3];
  const float* Wk = (const float*)d_in[4];
  const float* bk = (const float*)d_in[5];
  const float* Wv = (const float*)d_in[6];
  const float* bv = (const float*)d_in[7];
  float* out = (float*)d_out;
  char* ws = (char*)d_ws;

  u16* hb    = (u16*)(ws + 0x00000000);   // 8192x512 bf16      (8.0 MiB)
  u16* wt    = (u16*)(ws + 0x00900000);   // 1536x512 bf16      (1.5 MiB)
  float* bc  = (float*)(ws + 0x00B00000); // 1536 f32
  float* invf= (float*)(ws + 0x00B02000); // 32 f32
  u16* qws   = (u16*)(ws + 0x00C00000);   // 16x4096x64 bf16    (8 MiB)
  u16* kws   = (u16*)(ws + 0x01400000);   // 16x4096x64 bf16
  u16* vtws  = (u16*)(ws + 0x01C00000);   // 16x64x4096 bf16

  k_cast_hidden<<<dim3(2048), dim3(256), 0, stream>>>(hidden, hb, (2 * 4096 * 512) / 4);
  k_prep_w<<<dim3(1024), dim3(256), 0, stream>>>(Wq, Wk, Wv, bq, bk, bv, wt, bc, invf);
  k_proj<<<dim3(64, 12), dim3(256), 0, stream>>>(hb, wt, bc, invf, qws, kws, vtws);
  k_attn<<<dim3(512), dim3(256), 0, stream>>>(qws, kws, vtws, mask, out);
}

// Round 3
// 192.707 us; speedup vs baseline: 1.6320x; 1.1360x over previous
//
#include <hip/hip_runtime.h>
#include <hip/hip_bf16.h>
#include <math.h>

typedef __bf16 bf16_t;
typedef bf16_t bf16x8 __attribute__((ext_vector_type(8)));
typedef bf16_t bf16x2 __attribute__((ext_vector_type(2)));
typedef float f32x2 __attribute__((ext_vector_type(2)));
typedef float f32x4 __attribute__((ext_vector_type(4)));
typedef float f32x16 __attribute__((ext_vector_type(16)));
typedef unsigned short u16;
typedef unsigned int u32;
typedef u32 u32x2 __attribute__((ext_vector_type(2)));
typedef u32 u32x4 __attribute__((ext_vector_type(4)));

#define AS1 __attribute__((address_space(1)))
#define AS3 __attribute__((address_space(3)))

#define LOG2E 1.4426950408889634f

static __device__ __forceinline__ void gll16(const void* g, void* l){
  __builtin_amdgcn_global_load_lds((const AS1 u32*)g, (AS3 u32*)l, 16, 0, 0);
}

static __device__ __forceinline__ u16 f2bf(float f){
  u32 u = __builtin_bit_cast(u32, f);
  u = u + 0x7FFFu + ((u >> 16) & 1u);
  return (u16)(u >> 16);
}

static __device__ __forceinline__ u32 pk2(float a, float b){
  f32x2 v = {a, b};
  bf16x2 w = __builtin_convertvector(v, bf16x2);
  return __builtin_bit_cast(u32, w);
}

static __device__ __forceinline__ float ex2(float x){
#if __has_builtin(__builtin_amdgcn_exp2f)
  return __builtin_amdgcn_exp2f(x);
#else
  return __expf(0.6931471805599453f * x);
#endif
}

// exchange halves across lane<32 / lane>=32
static __device__ __forceinline__ void swap32(u32& a, u32& b, int hi){
#if __has_builtin(__builtin_amdgcn_permlane32_swap)
  auto r = __builtin_amdgcn_permlane32_swap((int)a, (int)b, false, false);
  a = (u32)r[0];
  b = (u32)r[1];
#else
  u32 xa = (u32)__shfl_xor((int)a, 32);
  u32 xb = (u32)__shfl_xor((int)b, 32);
  u32 na = hi ? xb : a;
  u32 nb = hi ? b : xa;
  a = na; b = nb;
#endif
}

// ---------------- prep: cast hidden fp32 -> bf16 ----------------
__global__ void k_cast_hidden(const float* __restrict__ h, u16* __restrict__ hb, int n4){
  int i = blockIdx.x * blockDim.x + threadIdx.x;
  int stride = gridDim.x * blockDim.x;
  for (; i < n4; i += stride){
    float4 v = ((const float4*)h)[i];
    ushort4 o;
    o.x = f2bf(v.x); o.y = f2bf(v.y); o.z = f2bf(v.z); o.w = f2bf(v.w);
    ((ushort4*)hb)[i] = o;
  }
}

// ---------------- prep: W^T concat via LDS tiles (coalesced both sides) ----------------
// grid: 192 blocks = 3 types x 8x8 tiles of 64x64
__global__ __launch_bounds__(256) void k_prep_w(const float* __restrict__ Wq, const float* __restrict__ Wk,
                         const float* __restrict__ Wv, const float* __restrict__ bq,
                         const float* __restrict__ bk, const float* __restrict__ bv,
                         u16* __restrict__ wt, float* __restrict__ bc, float* __restrict__ invf){
  __shared__ float T[64][65];
  int blk = blockIdx.x;
  int t = blk >> 6, rem = blk & 63;
  int tj = rem >> 3, tk = rem & 7;
  int j0 = tj * 64, k0 = tk * 64;
  const float* W = (t == 0) ? Wq : (t == 1 ? Wk : Wv);
  int tid = threadIdx.x;

  // load W[k0+r][j0+c], coalesced float4 rows
#pragma unroll
  for (int it = 0; it < 4; ++it){
    int idx = it * 256 + tid;
    int r = idx >> 4, c4 = idx & 15;
    float4 v = *(const float4*)&W[(size_t)(k0 + r) * 512 + j0 + c4 * 4];
    T[r][c4 * 4 + 0] = v.x; T[r][c4 * 4 + 1] = v.y;
    T[r][c4 * 4 + 2] = v.z; T[r][c4 * 4 + 3] = v.w;
  }
  __syncthreads();

  // write wt[(t*512 + j0 + rr)*512 + k0 + cc] = bf16(T[cc][rr]), 16B stores
#pragma unroll
  for (int it = 0; it < 2; ++it){
    int idx = it * 256 + tid;
    int rr = idx >> 3, g8 = idx & 7;
    u32x4 wv;
#pragma unroll
    for (int e = 0; e < 4; ++e)
      wv[e] = pk2(T[g8 * 8 + 2 * e][rr], T[g8 * 8 + 2 * e + 1][rr]);
    *(u32x4*)&wt[(size_t)(t * 512 + j0 + rr) * 512 + k0 + g8 * 8] = wv;
  }

  // bias concat (first 6 blocks) + inv_freq (block 0)
  int gi = blk * 256 + tid;
  if (gi < 1536){
    int tt = gi >> 9, jj = gi & 511;
    const float* bsrc = (tt == 0) ? bq : (tt == 1 ? bk : bv);
    bc[gi] = bsrc[jj];
  }
  if (blk == 0 && tid < 32){
    invf[tid] = 1.0f / (float)pow(10000.0, (double)(2 * tid) / 64.0);
  }
}

// ---------------- fused QKV GEMM + bias + RoPE + layout ----------------
// out: q,k as [slice=b*8+h][4096][64] bf16 (q pre-scaled by 0.125), v as [slice][64][4096] bf16 (transposed)
__global__ __launch_bounds__(256) void k_proj(const u16* __restrict__ hb, const u16* __restrict__ wt,
                      const float* __restrict__ bc, const float* __restrict__ invf,
                      u16* __restrict__ qws, u16* __restrict__ kws, u16* __restrict__ vt){
  __shared__ __align__(16) u16 SH[2][128 * 64];
  u16* At = SH[0];
  u16* Bt = SH[1];
  int tid = threadIdx.x;
  int lane = tid & 63;
  int c = lane & 15, g = lane >> 4;
  int wave = tid >> 6;
  int wm = wave >> 1, wn = wave & 1;
  int m0 = blockIdx.x * 128;
  int n0 = blockIdx.y * 128;

  const f32x4 vzero = {0.f, 0.f, 0.f, 0.f};
  f32x4 acc[4][4];
#pragma unroll
  for (int a = 0; a < 4; ++a)
#pragma unroll
    for (int b2 = 0; b2 < 4; ++b2) acc[a][b2] = vzero;

  for (int kc = 0; kc < 512; kc += 64){
    __syncthreads();
#pragma unroll
    for (int it = 0; it < 4; ++it){
      int j16 = it * 256 + tid;               // 1024 16B-units per tile
      int row = j16 >> 3, u = j16 & 7;
      int us = u ^ (row & 7);                 // pre-swizzled global source
      gll16(hb + (size_t)(m0 + row) * 512 + kc + us * 8, &At[j16 * 8]);
      gll16(wt + (size_t)(n0 + row) * 512 + kc + us * 8, &Bt[j16 * 8]);
    }
    __syncthreads();
#pragma unroll
    for (int ch = 0; ch < 2; ++ch){
      bf16x8 af[4], bfg[4];
#pragma unroll
      for (int mt = 0; mt < 4; ++mt){
        int r = wm * 64 + mt * 16 + c;
        af[mt] = *(const bf16x8*)&At[r * 64 + ((g + 4 * ch) ^ (r & 7)) * 8];
      }
#pragma unroll
      for (int nt = 0; nt < 4; ++nt){
        int r = wn * 64 + nt * 16 + c;
        bfg[nt] = *(const bf16x8*)&Bt[r * 64 + ((g + 4 * ch) ^ (r & 7)) * 8];
      }
#pragma unroll
      for (int mt = 0; mt < 4; ++mt)
#pragma unroll
        for (int nt = 0; nt < 4; ++nt)
          acc[mt][nt] = __builtin_amdgcn_mfma_f32_16x16x32_bf16(af[mt], bfg[nt], acc[mt][nt], 0, 0, 0);
    }
  }

  int colbase = n0 + wn * 64;                 // multiple of 64 -> single (type, head)
  int typ = colbase >> 9;                     // 0=q 1=k 2=v (block-uniform)
  int head = (colbase >> 6) & 7;
  int rowbase = m0 + wm * 64;
  int bb = rowbase >> 12, s0 = rowbase & 4095;
  float bias[4];
#pragma unroll
  for (int nt = 0; nt < 4; ++nt) bias[nt] = bc[colbase + nt * 16 + c];

  if (typ == 2){
    // V: transpose 64x64 wave tile through LDS, then 128B-coalesced stores of vt[d][s]
    __syncthreads();                          // protect SH reuse
    u16* Tw = &SH[0][0] + wave * 4096;        // 8KB per wave
#pragma unroll
    for (int nt = 0; nt < 4; ++nt){
      int n = nt * 16 + c;
#pragma unroll
      for (int mt = 0; mt < 4; ++mt){
        float y0 = acc[mt][0 + nt][0];  // placeholder to keep structure clear
        (void)y0;
        float a0 = acc[mt][nt][0] + bias[nt];
        float a1 = acc[mt][nt][1] + bias[nt];
        float a2 = acc[mt][nt][2] + bias[nt];
        float a3 = acc[mt][nt][3] + bias[nt];
        int p = (mt * 4 + g) ^ (c & 14);      // swizzled 8B unit
        u32x2 wv = { pk2(a0, a1), pk2(a2, a3) };
        *(u32x2*)&Tw[n * 64 + p * 4] = wv;
      }
    }
    __syncthreads();
    size_t vbase = (size_t)(bb * 8 + head) * 64 * 4096;
#pragma unroll
    for (int pass = 0; pass < 8; ++pass){
      int n = pass * 8 + (lane >> 3);
      int lu = (lane & 7) * 2;
      int p = lu ^ (n & 14);
      u32x4 vv = *(const u32x4*)&Tw[n * 64 + p * 4];
      *(u32x4*)&vt[vbase + (size_t)n * 4096 + s0 + (lane & 7) * 8] = vv;
    }
  } else {
    float fi[4];
#pragma unroll
    for (int nt = 0; nt < 4; ++nt) fi[nt] = invf[(nt * 16 + c) >> 1];
    u16* dst = (typ == 0) ? qws : kws;
    float scale = (typ == 0) ? 0.125f : 1.0f;   // fold 1/sqrt(64) into q
#pragma unroll
    for (int mt = 0; mt < 4; ++mt){
#pragma unroll
      for (int reg = 0; reg < 4; ++reg){
        int m = rowbase + mt * 16 + g * 4 + reg;
        int b = m >> 12, s = m & 4095;
        float sp = (float)s;
        size_t base = ((size_t)(b * 8 + head) * 4096 + s) * 64;
#pragma unroll
        for (int nt = 0; nt < 4; ++nt){
          float y = acc[mt][nt][reg] + bias[nt];
          float ang = sp * fi[nt];
          float cv, sn;
          sincosf(ang, &sn, &cv);
          int nn = nt * 16 + c;
          float rot;
          if (nn < 32){
            float y2 = acc[mt][nt + 2][reg] + bias[nt + 2];  // nn+32 partner
            rot = -y2;
          } else {
            float y2 = acc[mt][nt - 2][reg] + bias[nt - 2];
            rot = y2;
          }
          float o = (y * cv + rot * sn) * scale;
          dst[base + nn] = f2bf(o);
        }
      }
    }
  }
}

// ---------------- flash attention: 4 waves x 32q, 32x32x16 MFMA, in-register softmax ----------------
__global__ __launch_bounds__(256) void k_attn(const u16* __restrict__ qws, const u16* __restrict__ kws,
                      const u16* __restrict__ vtws, const float* __restrict__ mask,
                      float* __restrict__ out){
  __shared__ __align__(16) u16 smem[2][2][64 * 64];  // [buf][K=0/Vt=1][row*64+d], XOR-swizzled 16B units

  int tid = threadIdx.x;
  int lane = tid & 63;
  int q = lane & 31, hi = lane >> 5;
  int wave = tid >> 6;

  // XCD-aware bijective swizzle: 512 blocks, 8 XCDs -> 2 slices per XCD (K/V L2-resident)
  int nbid = (blockIdx.x & 7) * 64 + (blockIdx.x >> 3);
  int slice = nbid >> 5;                            // b*8+h
  int qt = nbid & 31;
  int b = slice >> 3, head = slice & 7;
  int q0 = qt * 128 + wave * 32;

  const u16* qs = qws + (size_t)slice * 4096 * 64;
  const u16* ks = kws + (size_t)slice * 4096 * 64;
  const u16* vs = vtws + (size_t)slice * 64 * 4096;
  const float* mk = mask + b * 4096;

  // Q fragments: B-operand, lane holds Q[q][d = dblk*16 + hi*8 + e], pre-scaled by 1/8
  const u16* qrow = qs + (size_t)(q0 + q) * 64;
  bf16x8 qf[4];
#pragma unroll
  for (int dblk = 0; dblk < 4; ++dblk)
    qf[dblk] = *(const bf16x8*)&qrow[dblk * 16 + hi * 8];

  const f32x16 vz = {0.f,0.f,0.f,0.f,0.f,0.f,0.f,0.f,0.f,0.f,0.f,0.f,0.f,0.f,0.f,0.f};
  f32x16 ctx0 = vz, ctx1 = vz;
  float m_run = -1e30f, l_run = 0.f;
  float ml = m_run * LOG2E;

  auto stage = [&](int buf, int kc){
#pragma unroll
    for (int it = 0; it < 2; ++it){
      int j = it * 256 + tid;                      // 512 16B-units per tile
      int row = j >> 3, u = j & 7;
      int us = u ^ (row & 7);
      gll16(ks + (size_t)(kc + row) * 64 + us * 8, &smem[buf][0][j * 8]);
      gll16(vs + (size_t)row * 4096 + kc + us * 8, &smem[buf][1][j * 8]);
    }
  };

  stage(0, 0);

  for (int t = 0; t < 64; ++t){
    __syncthreads();                               // drains vmcnt -> buf[t&1] ready
    if (t < 63) stage((t + 1) & 1, (t + 1) * 64);  // prefetch overlaps with compute below
    const u16* Kb  = &smem[t & 1][0][0];
    const u16* Vtc = &smem[t & 1][1][0];
    int kc = t * 64;

    // QK^T (swapped): S^T[key][q], acc reg -> key = (reg&3)+8*(reg>>2)+4*hi (+32*kb)
    f32x16 sv[2];
#pragma unroll
    for (int kb = 0; kb < 2; ++kb){
      f32x16 acc = vz;
#pragma unroll
      for (int dblk = 0; dblk < 4; ++dblk){
        int row = kb * 32 + q;
        bf16x8 kf = *(const bf16x8*)&Kb[row * 64 + (((dblk * 2 + hi) ^ (row & 7)) * 8)];
        acc = __builtin_amdgcn_mfma_f32_32x32x16_bf16(kf, qf[dblk], acc, 0, 0, 0);
      }
      // add attention mask (per key, uniform over q)
#pragma unroll
      for (int gg = 0; gg < 4; ++gg){
        float4 m4 = *(const float4*)&mk[kc + kb * 32 + gg * 8 + hi * 4];
        acc[4 * gg + 0] += m4.x;
        acc[4 * gg + 1] += m4.y;
        acc[4 * gg + 2] += m4.z;
        acc[4 * gg + 3] += m4.w;
      }
      sv[kb] = acc;
    }

    // tile max: tree reduce (max3-fusable), then cross-half
    float tm[8];
#pragma unroll
    for (int i = 0; i < 8; ++i)
      tm[i] = fmaxf(fmaxf(sv[0][2 * i], sv[0][2 * i + 1]),
                    fmaxf(sv[1][2 * i], sv[1][2 * i + 1]));
    float pmax = fmaxf(fmaxf(fmaxf(tm[0], tm[1]), fmaxf(tm[2], tm[3])),
                       fmaxf(fmaxf(tm[4], tm[5]), fmaxf(tm[6], tm[7])));
    pmax = fmaxf(pmax, __shfl_xor(pmax, 32));

    // defer-max (T13): rescale only when max grew past threshold
    if (__any(pmax > m_run + 8.f)){
      float mnew = fmaxf(m_run, pmax);
      float al = ex2((m_run - mnew) * LOG2E);
      m_run = mnew;
      ml = mnew * LOG2E;
      l_run *= al;
#pragma unroll
      for (int r = 0; r < 16; ++r){ ctx0[r] *= al; ctx1[r] *= al; }
    }

    // p = exp2(s*log2e - ml); 4 independent sum chains
    float rsp[4] = {0.f, 0.f, 0.f, 0.f};
#pragma unroll
    for (int kb = 0; kb < 2; ++kb)
#pragma unroll
      for (int r = 0; r < 16; ++r){
        float p = ex2(fmaf(sv[kb][r], LOG2E, -ml));
        sv[kb][r] = p;
        rsp[r & 3] += p;
      }
    float rs = (rsp[0] + rsp[1]) + (rsp[2] + rsp[3]);
    rs += __shfl_xor(rs, 32);
    l_run += rs;

    // pack P to bf16 words: W0/W1[kb][g] cover regs 4g..4g+3
    u32 W0[2][4], W1[2][4];
#pragma unroll
    for (int kb = 0; kb < 2; ++kb)
#pragma unroll
      for (int g = 0; g < 4; ++g){
        W0[kb][g] = pk2(sv[kb][4 * g + 0], sv[kb][4 * g + 1]);
        W1[kb][g] = pk2(sv[kb][4 * g + 2], sv[kb][4 * g + 3]);
      }

    // assemble PV B-frags (P^T): lane needs keys 16*kblk + 8*hi + 0..7 for its q
    bf16x8 pb[4];
#pragma unroll
    for (int kblk = 0; kblk < 4; ++kblk){
      int kb = kblk >> 1, j = kblk & 1;
      u32 w0 = W0[kb][2 * j + 0], w2 = W0[kb][2 * j + 1];
      u32 w1 = W1[kb][2 * j + 0], w3 = W1[kb][2 * j + 1];
      swap32(w0, w2, hi);
      swap32(w1, w3, hi);
      u32x4 wv = {w0, w1, w2, w3};
      pb[kblk] = __builtin_bit_cast(bf16x8, wv);
    }

    // PV: O^T[dv][q] += V^T[dv][key] * P^T[key][q]
#pragma unroll
    for (int kblk = 0; kblk < 4; ++kblk){
      int row0 = q;
      bf16x8 vf0 = *(const bf16x8*)&Vtc[row0 * 64 + (((kblk * 2 + hi) ^ (row0 & 7)) * 8)];
      ctx0 = __builtin_amdgcn_mfma_f32_32x32x16_bf16(vf0, pb[kblk], ctx0, 0, 0, 0);
      int row1 = 32 + q;
      bf16x8 vf1 = *(const bf16x8*)&Vtc[row1 * 64 + (((kblk * 2 + hi) ^ (row1 & 7)) * 8)];
      ctx1 = __builtin_amdgcn_mfma_f32_32x32x16_bf16(vf1, pb[kblk], ctx1, 0, 0, 0);
    }
  }

  // epilogue: O[q][dv] = ctx^T / l
  float invl = 1.0f / l_run;
  float* orow = out + (size_t)(b * 4096 + q0 + q) * 512 + head * 64;
#pragma unroll
  for (int g = 0; g < 4; ++g){
    float4 o0, o1;
    o0.x = ctx0[4 * g + 0] * invl; o0.y = ctx0[4 * g + 1] * invl;
    o0.z = ctx0[4 * g + 2] * invl; o0.w = ctx0[4 * g + 3] * invl;
    *(float4*)&orow[8 * g + 4 * hi] = o0;
    o1.x = ctx1[4 * g + 0] * invl; o1.y = ctx1[4 * g + 1] * invl;
    o1.z = ctx1[4 * g + 2] * invl; o1.w = ctx1[4 * g + 3] * invl;
    *(float4*)&orow[32 + 8 * g + 4 * hi] = o1;
  }
}

extern "C" void kernel_launch(void* const* d_in, const int* in_sizes, int n_in,
                              void* d_out, int out_size, void* d_ws, size_t ws_size,
                              hipStream_t stream) {
  const float* hidden = (const float*)d_in[0];
  const float* mask   = (const float*)d_in[1];
  const float* Wq = (const float*)d_in[2];
  const float* bq = (const float*)d_in[3];
  const float* Wk = (const float*)d_in[4];
  const float* bk = (const float*)d_in[5];
  const float* Wv = (const float*)d_in[6];
  const float* bv = (const float*)d_in[7];
  float* out = (float*)d_out;
  char* ws = (char*)d_ws;

  u16* hb    = (u16*)(ws + 0x00000000);   // 8192x512 bf16      (8.0 MiB)
  u16* wt    = (u16*)(ws + 0x00900000);   // 1536x512 bf16      (1.5 MiB)
  float* bc  = (float*)(ws + 0x00B00000); // 1536 f32
  float* invf= (float*)(ws + 0x00B02000); // 32 f32
  u16* qws   = (u16*)(ws + 0x00C00000);   // 16x4096x64 bf16    (8 MiB)
  u16* kws   = (u16*)(ws + 0x01400000);   // 16x4096x64 bf16
  u16* vtws  = (u16*)(ws + 0x01C00000);   // 16x64x4096 bf16

  k_cast_hidden<<<dim3(2048), dim3(256), 0, stream>>>(hidden, hb, (2 * 4096 * 512) / 4);
  k_prep_w<<<dim3(192), dim3(256), 0, stream>>>(Wq, Wk, Wv, bq, bk, bv, wt, bc, invf);
  k_proj<<<dim3(64, 12), dim3(256), 0, stream>>>(hb, wt, bc, invf, qws, kws, vtws);
  k_attn<<<dim3(512), dim3(256), 0, stream>>>(qws, kws, vtws, mask, out);
}

// Round 4
// 160.807 us; speedup vs baseline: 1.9558x; 1.1984x over previous
//
#include <hip/hip_runtime.h>
#include <hip/hip_bf16.h>
#include <math.h>

typedef __bf16 bf16_t;
typedef bf16_t bf16x8 __attribute__((ext_vector_type(8)));
typedef bf16_t bf16x2 __attribute__((ext_vector_type(2)));
typedef float f32x2 __attribute__((ext_vector_type(2)));
typedef float f32x4 __attribute__((ext_vector_type(4)));
typedef float f32x16 __attribute__((ext_vector_type(16)));
typedef unsigned short u16;
typedef unsigned int u32;
typedef u32 u32x2 __attribute__((ext_vector_type(2)));
typedef u32 u32x4 __attribute__((ext_vector_type(4)));

#define AS1 __attribute__((address_space(1)))
#define AS3 __attribute__((address_space(3)))

#define LOG2E 1.4426950408889634f

static __device__ __forceinline__ void gll16(const void* g, void* l){
  __builtin_amdgcn_global_load_lds((const AS1 u32*)g, (AS3 u32*)l, 16, 0, 0);
}

static __device__ __forceinline__ u16 f2bf(float f){
  u32 u = __builtin_bit_cast(u32, f);
  u = u + 0x7FFFu + ((u >> 16) & 1u);
  return (u16)(u >> 16);
}

static __device__ __forceinline__ u32 pk2(float a, float b){
  f32x2 v = {a, b};
  bf16x2 w = __builtin_convertvector(v, bf16x2);
  return __builtin_bit_cast(u32, w);
}

static __device__ __forceinline__ float ex2(float x){
#if __has_builtin(__builtin_amdgcn_exp2f)
  return __builtin_amdgcn_exp2f(x);
#else
  return __expf(0.6931471805599453f * x);
#endif
}

// exchange halves across lane<32 / lane>=32
static __device__ __forceinline__ void swap32(u32& a, u32& b, int hi){
#if __has_builtin(__builtin_amdgcn_permlane32_swap)
  auto r = __builtin_amdgcn_permlane32_swap((int)a, (int)b, false, false);
  a = (u32)r[0];
  b = (u32)r[1];
#else
  u32 xa = (u32)__shfl_xor((int)a, 32);
  u32 xb = (u32)__shfl_xor((int)b, 32);
  u32 na = hi ? xb : a;
  u32 nb = hi ? b : xa;
  a = na; b = nb;
#endif
}

// ---------------- prep: cast hidden fp32 -> bf16 ----------------
__global__ void k_cast_hidden(const float* __restrict__ h, u16* __restrict__ hb, int n4){
  int i = blockIdx.x * blockDim.x + threadIdx.x;
  int stride = gridDim.x * blockDim.x;
  for (; i < n4; i += stride){
    float4 v = ((const float4*)h)[i];
    ushort4 o;
    o.x = f2bf(v.x); o.y = f2bf(v.y); o.z = f2bf(v.z); o.w = f2bf(v.w);
    ((ushort4*)hb)[i] = o;
  }
}

// ---------------- prep: RoPE {cos,sin} pair table [4096][64] ----------------
__global__ __launch_bounds__(256) void k_rope(float* __restrict__ cs){
  int idx = blockIdx.x * 256 + threadIdx.x;   // 4096 * 32
  int s = idx >> 5, i = idx & 31;
  double invf = 1.0 / pow(10000.0, (double)(2 * i) / 64.0);
  float ang = (float)s * (float)invf;
  float sn, cv;
  sincosf(ang, &sn, &cv);
  f32x4 v = {cv, sn, cv, sn};                 // duplicate pair (repeat_interleave)
  *(f32x4*)&cs[(size_t)s * 128 + i * 4] = v;
}

// ---------------- prep: W^T concat via LDS tiles (coalesced both sides) ----------------
// grid: 192 blocks = 3 types x 8x8 tiles of 64x64
__global__ __launch_bounds__(256) void k_prep_w(const float* __restrict__ Wq, const float* __restrict__ Wk,
                         const float* __restrict__ Wv, const float* __restrict__ bq,
                         const float* __restrict__ bk, const float* __restrict__ bv,
                         u16* __restrict__ wt, float* __restrict__ bc){
  __shared__ float T[64][65];
  int blk = blockIdx.x;
  int t = blk >> 6, rem = blk & 63;
  int tj = rem >> 3, tk = rem & 7;
  int j0 = tj * 64, k0 = tk * 64;
  const float* W = (t == 0) ? Wq : (t == 1 ? Wk : Wv);
  int tid = threadIdx.x;

#pragma unroll
  for (int it = 0; it < 4; ++it){
    int idx = it * 256 + tid;
    int r = idx >> 4, c4 = idx & 15;
    float4 v = *(const float4*)&W[(size_t)(k0 + r) * 512 + j0 + c4 * 4];
    T[r][c4 * 4 + 0] = v.x; T[r][c4 * 4 + 1] = v.y;
    T[r][c4 * 4 + 2] = v.z; T[r][c4 * 4 + 3] = v.w;
  }
  __syncthreads();

#pragma unroll
  for (int it = 0; it < 2; ++it){
    int idx = it * 256 + tid;
    int rr = idx >> 3, g8 = idx & 7;
    u32x4 wv;
#pragma unroll
    for (int e = 0; e < 4; ++e)
      wv[e] = pk2(T[g8 * 8 + 2 * e][rr], T[g8 * 8 + 2 * e + 1][rr]);
    *(u32x4*)&wt[(size_t)(t * 512 + j0 + rr) * 512 + k0 + g8 * 8] = wv;
  }

  int gi = blk * 256 + tid;
  if (gi < 1536){
    int tt = gi >> 9, jj = gi & 511;
    const float* bsrc = (tt == 0) ? bq : (tt == 1 ? bk : bv);
    bc[gi] = bsrc[jj];
  }
}

// ---------------- fused QKV GEMM + bias + RoPE + layout ----------------
__global__ __launch_bounds__(256) void k_proj(const u16* __restrict__ hb, const u16* __restrict__ wt,
                      const float* __restrict__ bc, const float* __restrict__ cs,
                      u16* __restrict__ qws, u16* __restrict__ kws, u16* __restrict__ vt){
  __shared__ __align__(16) u16 SH[2][128 * 64];
  u16* At = SH[0];
  u16* Bt = SH[1];
  int tid = threadIdx.x;
  int lane = tid & 63;
  int c = lane & 15, g = lane >> 4;
  int wave = tid >> 6;
  int wm = wave >> 1, wn = wave & 1;
  int m0 = blockIdx.x * 128;
  int n0 = blockIdx.y * 128;

  const f32x4 vzero = {0.f, 0.f, 0.f, 0.f};
  f32x4 acc[4][4];
#pragma unroll
  for (int a = 0; a < 4; ++a)
#pragma unroll
    for (int b2 = 0; b2 < 4; ++b2) acc[a][b2] = vzero;

  for (int kc = 0; kc < 512; kc += 64){
    __syncthreads();
#pragma unroll
    for (int it = 0; it < 4; ++it){
      int j16 = it * 256 + tid;
      int row = j16 >> 3, u = j16 & 7;
      int us = u ^ (row & 7);
      gll16(hb + (size_t)(m0 + row) * 512 + kc + us * 8, &At[j16 * 8]);
      gll16(wt + (size_t)(n0 + row) * 512 + kc + us * 8, &Bt[j16 * 8]);
    }
    __syncthreads();
#pragma unroll
    for (int ch = 0; ch < 2; ++ch){
      bf16x8 af[4], bfg[4];
#pragma unroll
      for (int mt = 0; mt < 4; ++mt){
        int r = wm * 64 + mt * 16 + c;
        af[mt] = *(const bf16x8*)&At[r * 64 + ((g + 4 * ch) ^ (r & 7)) * 8];
      }
#pragma unroll
      for (int nt = 0; nt < 4; ++nt){
        int r = wn * 64 + nt * 16 + c;
        bfg[nt] = *(const bf16x8*)&Bt[r * 64 + ((g + 4 * ch) ^ (r & 7)) * 8];
      }
#pragma unroll
      for (int mt = 0; mt < 4; ++mt)
#pragma unroll
        for (int nt = 0; nt < 4; ++nt)
          acc[mt][nt] = __builtin_amdgcn_mfma_f32_16x16x32_bf16(af[mt], bfg[nt], acc[mt][nt], 0, 0, 0);
    }
  }

  int colbase = n0 + wn * 64;
  int typ = colbase >> 9;                     // 0=q 1=k 2=v (block-uniform)
  int head = (colbase >> 6) & 7;
  int rowbase = m0 + wm * 64;
  int bb = rowbase >> 12, s0 = rowbase & 4095;
  float bias[4];
#pragma unroll
  for (int nt = 0; nt < 4; ++nt) bias[nt] = bc[colbase + nt * 16 + c];

  if (typ == 2){
    // V: transpose 64x64 wave tile through LDS, then 128B-coalesced stores of vt[d][s]
    __syncthreads();
    u16* Tw = &SH[0][0] + wave * 4096;
#pragma unroll
    for (int nt = 0; nt < 4; ++nt){
      int n = nt * 16 + c;
#pragma unroll
      for (int mt = 0; mt < 4; ++mt){
        float a0 = acc[mt][nt][0] + bias[nt];
        float a1 = acc[mt][nt][1] + bias[nt];
        float a2 = acc[mt][nt][2] + bias[nt];
        float a3 = acc[mt][nt][3] + bias[nt];
        int p = (mt * 4 + g) ^ (c & 14);
        u32x2 wv = { pk2(a0, a1), pk2(a2, a3) };
        *(u32x2*)&Tw[n * 64 + p * 4] = wv;
      }
    }
    __syncthreads();
    size_t vbase = (size_t)(bb * 8 + head) * 64 * 4096;
#pragma unroll
    for (int pass = 0; pass < 8; ++pass){
      int n = pass * 8 + (lane >> 3);
      int lu = (lane & 7) * 2;
      int p = lu ^ (n & 14);
      u32x4 vv = *(const u32x4*)&Tw[n * 64 + p * 4];
      *(u32x4*)&vt[vbase + (size_t)n * 4096 + s0 + (lane & 7) * 8] = vv;
    }
  } else {
    u16* dst = (typ == 0) ? qws : kws;
    float scale = (typ == 0) ? 0.125f : 1.0f;
#pragma unroll
    for (int mt = 0; mt < 4; ++mt){
#pragma unroll
      for (int reg = 0; reg < 4; ++reg){
        int m = rowbase + mt * 16 + g * 4 + reg;
        int b = m >> 12, s = m & 4095;
        const f32x2* cs_s = (const f32x2*)(cs + (size_t)s * 128);
        size_t base = ((size_t)(b * 8 + head) * 4096 + s) * 64;
#pragma unroll
        for (int nt = 0; nt < 4; ++nt){
          int nn = nt * 16 + c;
          float y = acc[mt][nt][reg] + bias[nt];
          f32x2 p2 = cs_s[nn];
          float rot;
          if (nn < 32){
            rot = -(acc[mt][nt + 2][reg] + bias[nt + 2]);
          } else {
            rot = acc[mt][nt - 2][reg] + bias[nt - 2];
          }
          float o = (y * p2[0] + rot * p2[1]) * scale;
          dst[base + nn] = f2bf(o);
        }
      }
    }
  }
}

// ---------------- flash attention: 4 waves x 32q, 32x32x16 MFMA, in-register softmax ----------------
// NSPLIT=1: direct output. NSPLIT=2: write partial (ctx, m, l) per (split, row).
template<int NSPLIT>
__global__ __launch_bounds__(256, 4) void k_attn(const u16* __restrict__ qws, const u16* __restrict__ kws,
                      const u16* __restrict__ vtws, const float* __restrict__ mask,
                      float* __restrict__ out, float* __restrict__ pctx, float* __restrict__ pml){
  __shared__ __align__(16) u16 smem[2][2][64 * 64];

  int tid = threadIdx.x;
  int lane = tid & 63;
  int q = lane & 31, hi = lane >> 5;
  int wave = tid >> 6;

  // XCD-aware bijective swizzle (grid = 512*NSPLIT, multiple of 8)
  int cpx = (gridDim.x >> 3);
  int nbid = (blockIdx.x & 7) * cpx + (blockIdx.x >> 3);
  int slice = nbid / (32 * NSPLIT);
  int rem = nbid - slice * 32 * NSPLIT;
  int ksplit = rem >> 5;                       // 0..NSPLIT-1
  int qt = rem & 31;
  int b = slice >> 3, head = slice & 7;
  int q0 = qt * 128 + wave * 32;
  const int NT = 64 / NSPLIT;
  int kstart = ksplit * (4096 / NSPLIT);

  const u16* qs = qws + (size_t)slice * 4096 * 64;
  const u16* ks = kws + (size_t)slice * 4096 * 64;
  const u16* vs = vtws + (size_t)slice * 64 * 4096;
  const float* mk = mask + b * 4096;

  const u16* qrow = qs + (size_t)(q0 + q) * 64;
  bf16x8 qf[4];
#pragma unroll
  for (int dblk = 0; dblk < 4; ++dblk)
    qf[dblk] = *(const bf16x8*)&qrow[dblk * 16 + hi * 8];

  const f32x16 vz = {0.f,0.f,0.f,0.f,0.f,0.f,0.f,0.f,0.f,0.f,0.f,0.f,0.f,0.f,0.f,0.f};
  f32x16 ctx0 = vz, ctx1 = vz;
  float m_run = -1e30f, l_run = 0.f;
  float ml = m_run * LOG2E;

  auto stage = [&](int buf, int kc){
#pragma unroll
    for (int it = 0; it < 2; ++it){
      int j = it * 256 + tid;
      int row = j >> 3, u = j & 7;
      int us = u ^ (row & 7);
      gll16(ks + (size_t)(kc + row) * 64 + us * 8, &smem[buf][0][j * 8]);
      gll16(vs + (size_t)row * 4096 + kc + us * 8, &smem[buf][1][j * 8]);
    }
  };

  stage(0, kstart);

  for (int t = 0; t < NT; ++t){
    int kc = kstart + t * 64;
    __syncthreads();
    if (t < NT - 1) stage((t + 1) & 1, kc + 64);
    const u16* Kb  = &smem[t & 1][0][0];
    const u16* Vtc = &smem[t & 1][1][0];

    // QK^T (swapped): S^T[key][q]
    f32x16 sv[2];
    __builtin_amdgcn_s_setprio(1);
#pragma unroll
    for (int kb = 0; kb < 2; ++kb){
      f32x16 acc = vz;
#pragma unroll
      for (int dblk = 0; dblk < 4; ++dblk){
        int row = kb * 32 + q;
        bf16x8 kf = *(const bf16x8*)&Kb[row * 64 + (((dblk * 2 + hi) ^ (row & 7)) * 8)];
        acc = __builtin_amdgcn_mfma_f32_32x32x16_bf16(kf, qf[dblk], acc, 0, 0, 0);
      }
      sv[kb] = acc;
    }
    __builtin_amdgcn_s_setprio(0);
#pragma unroll
    for (int kb = 0; kb < 2; ++kb)
#pragma unroll
      for (int gg = 0; gg < 4; ++gg){
        float4 m4 = *(const float4*)&mk[kc + kb * 32 + gg * 8 + hi * 4];
        sv[kb][4 * gg + 0] += m4.x;
        sv[kb][4 * gg + 1] += m4.y;
        sv[kb][4 * gg + 2] += m4.z;
        sv[kb][4 * gg + 3] += m4.w;
      }

    // tile max: max3-shaped triple tree over 32 values
#define SVV(j) sv[(j) >> 4][(j) & 15]
    float tr[11];
#pragma unroll
    for (int i = 0; i < 10; ++i)
      tr[i] = fmaxf(fmaxf(SVV(3 * i), SVV(3 * i + 1)), SVV(3 * i + 2));
    tr[10] = fmaxf(SVV(30), SVV(31));
#undef SVV
    float u0 = fmaxf(fmaxf(tr[0], tr[1]), tr[2]);
    float u1 = fmaxf(fmaxf(tr[3], tr[4]), tr[5]);
    float u2 = fmaxf(fmaxf(tr[6], tr[7]), tr[8]);
    float u3 = fmaxf(tr[9], tr[10]);
    float pmax = fmaxf(fmaxf(fmaxf(u0, u1), u2), u3);
    pmax = fmaxf(pmax, __shfl_xor(pmax, 32));

    // defer-max (T13)
    if (__any(pmax > m_run + 8.f)){
      float mnew = fmaxf(m_run, pmax);
      float al = ex2((m_run - mnew) * LOG2E);
      m_run = mnew;
      ml = mnew * LOG2E;
      l_run *= al;
#pragma unroll
      for (int r = 0; r < 16; ++r){ ctx0[r] *= al; ctx1[r] *= al; }
    }

    float rsp[4] = {0.f, 0.f, 0.f, 0.f};
#pragma unroll
    for (int kb = 0; kb < 2; ++kb)
#pragma unroll
      for (int r = 0; r < 16; ++r){
        float p = ex2(fmaf(sv[kb][r], LOG2E, -ml));
        sv[kb][r] = p;
        rsp[r & 3] += p;
      }
    float rs = (rsp[0] + rsp[1]) + (rsp[2] + rsp[3]);
    rs += __shfl_xor(rs, 32);
    l_run += rs;

    u32 W0[2][4], W1[2][4];
#pragma unroll
    for (int kb = 0; kb < 2; ++kb)
#pragma unroll
      for (int g = 0; g < 4; ++g){
        W0[kb][g] = pk2(sv[kb][4 * g + 0], sv[kb][4 * g + 1]);
        W1[kb][g] = pk2(sv[kb][4 * g + 2], sv[kb][4 * g + 3]);
      }

    bf16x8 pb[4];
#pragma unroll
    for (int kblk = 0; kblk < 4; ++kblk){
      int kb = kblk >> 1, j = kblk & 1;
      u32 w0 = W0[kb][2 * j + 0], w2 = W0[kb][2 * j + 1];
      u32 w1 = W1[kb][2 * j + 0], w3 = W1[kb][2 * j + 1];
      swap32(w0, w2, hi);
      swap32(w1, w3, hi);
      u32x4 wv = {w0, w1, w2, w3};
      pb[kblk] = __builtin_bit_cast(bf16x8, wv);
    }

    __builtin_amdgcn_s_setprio(1);
#pragma unroll
    for (int kblk = 0; kblk < 4; ++kblk){
      int row0 = q;
      bf16x8 vf0 = *(const bf16x8*)&Vtc[row0 * 64 + (((kblk * 2 + hi) ^ (row0 & 7)) * 8)];
      ctx0 = __builtin_amdgcn_mfma_f32_32x32x16_bf16(vf0, pb[kblk], ctx0, 0, 0, 0);
      int row1 = 32 + q;
      bf16x8 vf1 = *(const bf16x8*)&Vtc[row1 * 64 + (((kblk * 2 + hi) ^ (row1 & 7)) * 8)];
      ctx1 = __builtin_amdgcn_mfma_f32_32x32x16_bf16(vf1, pb[kblk], ctx1, 0, 0, 0);
    }
    __builtin_amdgcn_s_setprio(0);
  }

  if (NSPLIT == 1){
    float invl = 1.0f / l_run;
    float* orow = out + (size_t)(b * 4096 + q0 + q) * 512 + head * 64;
#pragma unroll
    for (int g = 0; g < 4; ++g){
      float4 o0, o1;
      o0.x = ctx0[4 * g + 0] * invl; o0.y = ctx0[4 * g + 1] * invl;
      o0.z = ctx0[4 * g + 2] * invl; o0.w = ctx0[4 * g + 3] * invl;
      *(float4*)&orow[8 * g + 4 * hi] = o0;
      o1.x = ctx1[4 * g + 0] * invl; o1.y = ctx1[4 * g + 1] * invl;
      o1.z = ctx1[4 * g + 2] * invl; o1.w = ctx1[4 * g + 3] * invl;
      *(float4*)&orow[32 + 8 * g + 4 * hi] = o1;
    }
  } else {
    size_t row = (size_t)ksplit * 65536 + slice * 4096 + q0 + q;
    float* prow = pctx + row * 64;
#pragma unroll
    for (int g = 0; g < 4; ++g){
      float4 o0, o1;
      o0.x = ctx0[4 * g + 0]; o0.y = ctx0[4 * g + 1];
      o0.z = ctx0[4 * g + 2]; o0.w = ctx0[4 * g + 3];
      *(float4*)&prow[8 * g + 4 * hi] = o0;
      o1.x = ctx1[4 * g + 0]; o1.y = ctx1[4 * g + 1];
      o1.z = ctx1[4 * g + 2]; o1.w = ctx1[4 * g + 3];
      *(float4*)&prow[32 + 8 * g + 4 * hi] = o1;
    }
    if (hi == 0){
      f32x2 mlv = {m_run, l_run};
      *(f32x2*)&pml[row * 2] = mlv;
    }
  }
}

// ---------------- split-K merge ----------------
__global__ __launch_bounds__(256) void k_merge(const float* __restrict__ pctx, const float* __restrict__ pml,
                                               float* __restrict__ out){
  int idx = blockIdx.x * 256 + threadIdx.x;   // 65536 rows * 16 quads
  int row = idx >> 4, dq = (idx & 15) * 4;
  f32x2 ml0 = *(const f32x2*)&pml[(size_t)row * 2];
  f32x2 ml1 = *(const f32x2*)&pml[((size_t)65536 + row) * 2];
  float ms = fmaxf(ml0[0], ml1[0]);
  float w0 = ex2((ml0[0] - ms) * LOG2E);
  float w1 = ex2((ml1[0] - ms) * LOG2E);
  float rdenom = 1.0f / (w0 * ml0[1] + w1 * ml1[1]);
  float4 c0 = *(const float4*)&pctx[(size_t)row * 64 + dq];
  float4 c1 = *(const float4*)&pctx[((size_t)65536 + row) * 64 + dq];
  float4 o;
  o.x = (w0 * c0.x + w1 * c1.x) * rdenom;
  o.y = (w0 * c0.y + w1 * c1.y) * rdenom;
  o.z = (w0 * c0.z + w1 * c1.z) * rdenom;
  o.w = (w0 * c0.w + w1 * c1.w) * rdenom;
  int slice = row >> 12, s = row & 4095;
  int b = slice >> 3, head = slice & 7;
  *(float4*)&out[(size_t)(b * 4096 + s) * 512 + head * 64 + dq] = o;
}

extern "C" void kernel_launch(void* const* d_in, const int* in_sizes, int n_in,
                              void* d_out, int out_size, void* d_ws, size_t ws_size,
                              hipStream_t stream) {
  const float* hidden = (const float*)d_in[0];
  const float* mask   = (const float*)d_in[1];
  const float* Wq = (const float*)d_in[2];
  const float* bq = (const float*)d_in[3];
  const float* Wk = (const float*)d_in[4];
  const float* bk = (const float*)d_in[5];
  const float* Wv = (const float*)d_in[6];
  const float* bv = (const float*)d_in[7];
  float* out = (float*)d_out;
  char* ws = (char*)d_ws;

  u16* hb    = (u16*)(ws + 0x00000000);   // 8192x512 bf16      (8 MiB)
  u16* wt    = (u16*)(ws + 0x00900000);   // 1536x512 bf16      (1.5 MiB)
  float* bc  = (float*)(ws + 0x00B00000); // 1536 f32
  float* cs  = (float*)(ws + 0x00B10000); // 4096x64x2 f32      (2 MiB)
  u16* qws   = (u16*)(ws + 0x00E00000);   // 16x4096x64 bf16    (8 MiB)
  u16* kws   = (u16*)(ws + 0x01600000);   // 16x4096x64 bf16
  u16* vtws  = (u16*)(ws + 0x01E00000);   // 16x64x4096 bf16
  float* pctx= (float*)(ws + 0x02600000); // 2x65536x64 f32     (32 MiB)
  float* pml = (float*)(ws + 0x04600000); // 2x65536x2 f32      (1 MiB)

  bool split = ws_size >= 0x04700000ull;

  k_cast_hidden<<<dim3(2048), dim3(256), 0, stream>>>(hidden, hb, (2 * 4096 * 512) / 4);
  k_rope<<<dim3(512), dim3(256), 0, stream>>>(cs);
  k_prep_w<<<dim3(192), dim3(256), 0, stream>>>(Wq, Wk, Wv, bq, bk, bv, wt, bc);
  k_proj<<<dim3(64, 12), dim3(256), 0, stream>>>(hb, wt, bc, cs, qws, kws, vtws);
  if (split){
    k_attn<2><<<dim3(1024), dim3(256), 0, stream>>>(qws, kws, vtws, mask, out, pctx, pml);
    k_merge<<<dim3(4096), dim3(256), 0, stream>>>(pctx, pml, out);
  } else {
    k_attn<1><<<dim3(512), dim3(256), 0, stream>>>(qws, kws, vtws, mask, out, pctx, pml);
  }
}

// Round 5
// 154.354 us; speedup vs baseline: 2.0376x; 1.0418x over previous
//
#include <hip/hip_runtime.h>
#include <hip/hip_bf16.h>
#include <math.h>

typedef __bf16 bf16_t;
typedef bf16_t bf16x8 __attribute__((ext_vector_type(8)));
typedef bf16_t bf16x2 __attribute__((ext_vector_type(2)));
typedef float f32x2 __attribute__((ext_vector_type(2)));
typedef float f32x4 __attribute__((ext_vector_type(4)));
typedef float f32x16 __attribute__((ext_vector_type(16)));
typedef unsigned short u16;
typedef unsigned int u32;
typedef u32 u32x2 __attribute__((ext_vector_type(2)));
typedef u32 u32x4 __attribute__((ext_vector_type(4)));

#define AS1 __attribute__((address_space(1)))
#define AS3 __attribute__((address_space(3)))

#define LOG2E 1.4426950408889634f

static __device__ __forceinline__ void gll16(const void* g, void* l){
  __builtin_amdgcn_global_load_lds((const AS1 u32*)g, (AS3 u32*)l, 16, 0, 0);
}

static __device__ __forceinline__ u16 f2bf(float f){
  u32 u = __builtin_bit_cast(u32, f);
  u = u + 0x7FFFu + ((u >> 16) & 1u);
  return (u16)(u >> 16);
}

static __device__ __forceinline__ u32 pk2(float a, float b){
  f32x2 v = {a, b};
  bf16x2 w = __builtin_convertvector(v, bf16x2);
  return __builtin_bit_cast(u32, w);
}

static __device__ __forceinline__ float ex2(float x){
#if __has_builtin(__builtin_amdgcn_exp2f)
  return __builtin_amdgcn_exp2f(x);
#else
  return __expf(0.6931471805599453f * x);
#endif
}

// exchange halves across lane<32 / lane>=32
static __device__ __forceinline__ void swap32(u32& a, u32& b, int hi){
#if __has_builtin(__builtin_amdgcn_permlane32_swap)
  auto r = __builtin_amdgcn_permlane32_swap((int)a, (int)b, false, false);
  a = (u32)r[0];
  b = (u32)r[1];
#else
  u32 xa = (u32)__shfl_xor((int)a, 32);
  u32 xb = (u32)__shfl_xor((int)b, 32);
  u32 na = hi ? xb : a;
  u32 nb = hi ? b : xa;
  a = na; b = nb;
#endif
}

// ---------------- prep: cast hidden fp32 -> bf16 ----------------
__global__ void k_cast_hidden(const float* __restrict__ h, u16* __restrict__ hb, int n4){
  int i = blockIdx.x * blockDim.x + threadIdx.x;
  int stride = gridDim.x * blockDim.x;
  for (; i < n4; i += stride){
    float4 v = ((const float4*)h)[i];
    ushort4 o;
    o.x = f2bf(v.x); o.y = f2bf(v.y); o.z = f2bf(v.z); o.w = f2bf(v.w);
    ((ushort4*)hb)[i] = o;
  }
}

// ---------------- prep: RoPE {cos,sin} pair table [4096][64] ----------------
__global__ __launch_bounds__(256) void k_rope(float* __restrict__ cs){
  int idx = blockIdx.x * 256 + threadIdx.x;   // 4096 * 32
  int s = idx >> 5, i = idx & 31;
  double invf = 1.0 / pow(10000.0, (double)(2 * i) / 64.0);
  float ang = (float)s * (float)invf;
  float sn, cv;
  sincosf(ang, &sn, &cv);
  f32x4 v = {cv, sn, cv, sn};                 // duplicate pair (repeat_interleave)
  *(f32x4*)&cs[(size_t)s * 128 + i * 4] = v;
}

// ---------------- prep: W^T concat via LDS tiles (coalesced both sides) ----------------
__global__ __launch_bounds__(256) void k_prep_w(const float* __restrict__ Wq, const float* __restrict__ Wk,
                         const float* __restrict__ Wv, const float* __restrict__ bq,
                         const float* __restrict__ bk, const float* __restrict__ bv,
                         u16* __restrict__ wt, float* __restrict__ bc){
  __shared__ float T[64][65];
  int blk = blockIdx.x;
  int t = blk >> 6, rem = blk & 63;
  int tj = rem >> 3, tk = rem & 7;
  int j0 = tj * 64, k0 = tk * 64;
  const float* W = (t == 0) ? Wq : (t == 1 ? Wk : Wv);
  int tid = threadIdx.x;

#pragma unroll
  for (int it = 0; it < 4; ++it){
    int idx = it * 256 + tid;
    int r = idx >> 4, c4 = idx & 15;
    float4 v = *(const float4*)&W[(size_t)(k0 + r) * 512 + j0 + c4 * 4];
    T[r][c4 * 4 + 0] = v.x; T[r][c4 * 4 + 1] = v.y;
    T[r][c4 * 4 + 2] = v.z; T[r][c4 * 4 + 3] = v.w;
  }
  __syncthreads();

#pragma unroll
  for (int it = 0; it < 2; ++it){
    int idx = it * 256 + tid;
    int rr = idx >> 3, g8 = idx & 7;
    u32x4 wv;
#pragma unroll
    for (int e = 0; e < 4; ++e)
      wv[e] = pk2(T[g8 * 8 + 2 * e][rr], T[g8 * 8 + 2 * e + 1][rr]);
    *(u32x4*)&wt[(size_t)(t * 512 + j0 + rr) * 512 + k0 + g8 * 8] = wv;
  }

  int gi = blk * 256 + tid;
  if (gi < 1536){
    int tt = gi >> 9, jj = gi & 511;
    const float* bsrc = (tt == 0) ? bq : (tt == 1 ? bk : bv);
    bc[gi] = bsrc[jj];
  }
}

// ---------------- fused QKV GEMM + bias + RoPE + layout ----------------
__global__ __launch_bounds__(256) void k_proj(const u16* __restrict__ hb, const u16* __restrict__ wt,
                      const float* __restrict__ bc, const float* __restrict__ cs,
                      u16* __restrict__ qws, u16* __restrict__ kws, u16* __restrict__ vt){
  __shared__ __align__(16) u16 SH[2][128 * 64];
  u16* At = SH[0];
  u16* Bt = SH[1];
  int tid = threadIdx.x;
  int lane = tid & 63;
  int c = lane & 15, g = lane >> 4;
  int wave = tid >> 6;
  int wm = wave >> 1, wn = wave & 1;
  int m0 = blockIdx.x * 128;
  int n0 = blockIdx.y * 128;

  const f32x4 vzero = {0.f, 0.f, 0.f, 0.f};
  f32x4 acc[4][4];
#pragma unroll
  for (int a = 0; a < 4; ++a)
#pragma unroll
    for (int b2 = 0; b2 < 4; ++b2) acc[a][b2] = vzero;

  for (int kc = 0; kc < 512; kc += 64){
    __syncthreads();
#pragma unroll
    for (int it = 0; it < 4; ++it){
      int j16 = it * 256 + tid;
      int row = j16 >> 3, u = j16 & 7;
      int us = u ^ (row & 7);
      gll16(hb + (size_t)(m0 + row) * 512 + kc + us * 8, &At[j16 * 8]);
      gll16(wt + (size_t)(n0 + row) * 512 + kc + us * 8, &Bt[j16 * 8]);
    }
    __syncthreads();
#pragma unroll
    for (int ch = 0; ch < 2; ++ch){
      bf16x8 af[4], bfg[4];
#pragma unroll
      for (int mt = 0; mt < 4; ++mt){
        int r = wm * 64 + mt * 16 + c;
        af[mt] = *(const bf16x8*)&At[r * 64 + ((g + 4 * ch) ^ (r & 7)) * 8];
      }
#pragma unroll
      for (int nt = 0; nt < 4; ++nt){
        int r = wn * 64 + nt * 16 + c;
        bfg[nt] = *(const bf16x8*)&Bt[r * 64 + ((g + 4 * ch) ^ (r & 7)) * 8];
      }
#pragma unroll
      for (int mt = 0; mt < 4; ++mt)
#pragma unroll
        for (int nt = 0; nt < 4; ++nt)
          acc[mt][nt] = __builtin_amdgcn_mfma_f32_16x16x32_bf16(af[mt], bfg[nt], acc[mt][nt], 0, 0, 0);
    }
  }

  int colbase = n0 + wn * 64;
  int typ = colbase >> 9;                     // 0=q 1=k 2=v (block-uniform)
  int head = (colbase >> 6) & 7;
  int rowbase = m0 + wm * 64;
  int bb = rowbase >> 12, s0 = rowbase & 4095;
  float bias[4];
#pragma unroll
  for (int nt = 0; nt < 4; ++nt) bias[nt] = bc[colbase + nt * 16 + c];

  if (typ == 2){
    __syncthreads();
    u16* Tw = &SH[0][0] + wave * 4096;
#pragma unroll
    for (int nt = 0; nt < 4; ++nt){
      int n = nt * 16 + c;
#pragma unroll
      for (int mt = 0; mt < 4; ++mt){
        float a0 = acc[mt][nt][0] + bias[nt];
        float a1 = acc[mt][nt][1] + bias[nt];
        float a2 = acc[mt][nt][2] + bias[nt];
        float a3 = acc[mt][nt][3] + bias[nt];
        int p = (mt * 4 + g) ^ (c & 14);
        u32x2 wv = { pk2(a0, a1), pk2(a2, a3) };
        *(u32x2*)&Tw[n * 64 + p * 4] = wv;
      }
    }
    __syncthreads();
    size_t vbase = (size_t)(bb * 8 + head) * 64 * 4096;
#pragma unroll
    for (int pass = 0; pass < 8; ++pass){
      int n = pass * 8 + (lane >> 3);
      int lu = (lane & 7) * 2;
      int p = lu ^ (n & 14);
      u32x4 vv = *(const u32x4*)&Tw[n * 64 + p * 4];
      *(u32x4*)&vt[vbase + (size_t)n * 4096 + s0 + (lane & 7) * 8] = vv;
    }
  } else {
    u16* dst = (typ == 0) ? qws : kws;
    float scale = (typ == 0) ? 0.125f : 1.0f;
#pragma unroll
    for (int mt = 0; mt < 4; ++mt){
#pragma unroll
      for (int reg = 0; reg < 4; ++reg){
        int m = rowbase + mt * 16 + g * 4 + reg;
        int b = m >> 12, s = m & 4095;
        const f32x2* cs_s = (const f32x2*)(cs + (size_t)s * 128);
        size_t base = ((size_t)(b * 8 + head) * 4096 + s) * 64;
#pragma unroll
        for (int nt = 0; nt < 4; ++nt){
          int nn = nt * 16 + c;
          float y = acc[mt][nt][reg] + bias[nt];
          f32x2 p2 = cs_s[nn];
          float rot;
          if (nn < 32){
            rot = -(acc[mt][nt + 2][reg] + bias[nt + 2]);
          } else {
            rot = acc[mt][nt - 2][reg] + bias[nt - 2];
          }
          float o = (y * p2[0] + rot * p2[1]) * scale;
          dst[base + nn] = f2bf(o);
        }
      }
    }
  }
}

// ---------------- flash attention: 4 waves x 64q, 32x32x16 MFMA, in-register softmax ----------------
// Each K/V LDS fragment feeds 2 MFMAs (two q-halves). NSPLIT=2: partials to ws.
template<int NSPLIT>
__global__ __launch_bounds__(256, 2) void k_attn(const u16* __restrict__ qws, const u16* __restrict__ kws,
                      const u16* __restrict__ vtws, const float* __restrict__ mask,
                      float* __restrict__ out, float* __restrict__ pctx, float* __restrict__ pml){
  __shared__ __align__(16) u16 smem[2][2][64 * 64];

  int tid = threadIdx.x;
  int lane = tid & 63;
  int q = lane & 31, hi = lane >> 5;
  int wave = tid >> 6;

  // XCD-aware bijective swizzle (grid = 256*NSPLIT, multiple of 8)
  int cpx = (gridDim.x >> 3);
  int nbid = (blockIdx.x & 7) * cpx + (blockIdx.x >> 3);
  int slice = nbid / (16 * NSPLIT);
  int rem = nbid - slice * 16 * NSPLIT;
  int ksplit = rem >> 4;                       // 0..NSPLIT-1
  int qt = rem & 15;
  int b = slice >> 3, head = slice & 7;
  int q0 = qt * 256 + wave * 64;               // 64 q per wave
  const int NT = 64 / NSPLIT;
  int kstart = ksplit * (4096 / NSPLIT);

  const u16* qs = qws + (size_t)slice * 4096 * 64;
  const u16* ks = kws + (size_t)slice * 4096 * 64;
  const u16* vs = vtws + (size_t)slice * 64 * 4096;
  const float* mk = mask + b * 4096;

  // Q fragments for both q-halves: lane holds Q[q0 + h*32 + q][d]
  bf16x8 qf[2][4];
#pragma unroll
  for (int h = 0; h < 2; ++h){
    const u16* qrow = qs + (size_t)(q0 + h * 32 + q) * 64;
#pragma unroll
    for (int dblk = 0; dblk < 4; ++dblk)
      qf[h][dblk] = *(const bf16x8*)&qrow[dblk * 16 + hi * 8];
  }

  const f32x16 vz = {0.f,0.f,0.f,0.f,0.f,0.f,0.f,0.f,0.f,0.f,0.f,0.f,0.f,0.f,0.f,0.f};
  f32x16 ctx[2][2];                            // [h][dv-half]
#pragma unroll
  for (int h = 0; h < 2; ++h){ ctx[h][0] = vz; ctx[h][1] = vz; }
  float m_run[2] = {-1e30f, -1e30f}, l_run[2] = {0.f, 0.f};
  float ml[2] = {-1e30f * LOG2E, -1e30f * LOG2E};

  auto stage = [&](int buf, int kc){
#pragma unroll
    for (int it = 0; it < 2; ++it){
      int j = it * 256 + tid;
      int row = j >> 3, u = j & 7;
      int us = u ^ (row & 7);
      gll16(ks + (size_t)(kc + row) * 64 + us * 8, &smem[buf][0][j * 8]);
      gll16(vs + (size_t)row * 4096 + kc + us * 8, &smem[buf][1][j * 8]);
    }
  };

  stage(0, kstart);

  for (int t = 0; t < NT; ++t){
    int kc = kstart + t * 64;
    __syncthreads();
    if (t < NT - 1) stage((t + 1) & 1, kc + 64);
    const u16* Kb  = &smem[t & 1][0][0];
    const u16* Vtc = &smem[t & 1][1][0];

    // QK^T (swapped): S^T[key][q], kf shared by both q-halves
    f32x16 sv[2][2];                            // [h][kb]
    __builtin_amdgcn_s_setprio(1);
#pragma unroll
    for (int kb = 0; kb < 2; ++kb){
      f32x16 a0 = vz, a1 = vz;
#pragma unroll
      for (int dblk = 0; dblk < 4; ++dblk){
        int row = kb * 32 + q;
        bf16x8 kf = *(const bf16x8*)&Kb[row * 64 + (((dblk * 2 + hi) ^ (row & 7)) * 8)];
        a0 = __builtin_amdgcn_mfma_f32_32x32x16_bf16(kf, qf[0][dblk], a0, 0, 0, 0);
        a1 = __builtin_amdgcn_mfma_f32_32x32x16_bf16(kf, qf[1][dblk], a1, 0, 0, 0);
      }
      sv[0][kb] = a0;
      sv[1][kb] = a1;
    }
    __builtin_amdgcn_s_setprio(0);

    // mask add (per key, uniform over q): build vector once per kb, add to both halves
#pragma unroll
    for (int kb = 0; kb < 2; ++kb){
      f32x16 mv;
#pragma unroll
      for (int gg = 0; gg < 4; ++gg){
        float4 m4 = *(const float4*)&mk[kc + kb * 32 + gg * 8 + hi * 4];
        mv[4 * gg + 0] = m4.x; mv[4 * gg + 1] = m4.y;
        mv[4 * gg + 2] = m4.z; mv[4 * gg + 3] = m4.w;
      }
      sv[0][kb] = sv[0][kb] + mv;
      sv[1][kb] = sv[1][kb] + mv;
    }

#pragma unroll
    for (int h = 0; h < 2; ++h){
      // tile max: max3-shaped triple tree over 32 values
#define SVV(j) sv[h][(j) >> 4][(j) & 15]
      float tr[11];
#pragma unroll
      for (int i = 0; i < 10; ++i)
        tr[i] = fmaxf(fmaxf(SVV(3 * i), SVV(3 * i + 1)), SVV(3 * i + 2));
      tr[10] = fmaxf(SVV(30), SVV(31));
#undef SVV
      float u0 = fmaxf(fmaxf(tr[0], tr[1]), tr[2]);
      float u1 = fmaxf(fmaxf(tr[3], tr[4]), tr[5]);
      float u2 = fmaxf(fmaxf(tr[6], tr[7]), tr[8]);
      float u3 = fmaxf(tr[9], tr[10]);
      float pmax = fmaxf(fmaxf(fmaxf(u0, u1), u2), u3);
      pmax = fmaxf(pmax, __shfl_xor(pmax, 32));

      // defer-max (T13)
      if (__any(pmax > m_run[h] + 8.f)){
        float mnew = fmaxf(m_run[h], pmax);
        float al = ex2((m_run[h] - mnew) * LOG2E);
        m_run[h] = mnew;
        ml[h] = mnew * LOG2E;
        l_run[h] *= al;
#pragma unroll
        for (int r = 0; r < 16; ++r){ ctx[h][0][r] *= al; ctx[h][1][r] *= al; }
      }

      float rsp[4] = {0.f, 0.f, 0.f, 0.f};
#pragma unroll
      for (int kb = 0; kb < 2; ++kb)
#pragma unroll
        for (int r = 0; r < 16; ++r){
          float p = ex2(fmaf(sv[h][kb][r], LOG2E, -ml[h]));
          sv[h][kb][r] = p;
          rsp[r & 3] += p;
        }
      float rs = (rsp[0] + rsp[1]) + (rsp[2] + rsp[3]);
      rs += __shfl_xor(rs, 32);
      l_run[h] += rs;
    }

    // pack P and assemble PV B-frags per q-half
    bf16x8 pb[2][4];
#pragma unroll
    for (int h = 0; h < 2; ++h){
      u32 W0[2][4], W1[2][4];
#pragma unroll
      for (int kb = 0; kb < 2; ++kb)
#pragma unroll
        for (int g = 0; g < 4; ++g){
          W0[kb][g] = pk2(sv[h][kb][4 * g + 0], sv[h][kb][4 * g + 1]);
          W1[kb][g] = pk2(sv[h][kb][4 * g + 2], sv[h][kb][4 * g + 3]);
        }
#pragma unroll
      for (int kblk = 0; kblk < 4; ++kblk){
        int kb = kblk >> 1, j = kblk & 1;
        u32 w0 = W0[kb][2 * j + 0], w2 = W0[kb][2 * j + 1];
        u32 w1 = W1[kb][2 * j + 0], w3 = W1[kb][2 * j + 1];
        swap32(w0, w2, hi);
        swap32(w1, w3, hi);
        u32x4 wv = {w0, w1, w2, w3};
        pb[h][kblk] = __builtin_bit_cast(bf16x8, wv);
      }
    }

    // PV: O^T[dv][q] += V^T[dv][key] * P^T[key][q]; vf shared by both q-halves
    __builtin_amdgcn_s_setprio(1);
#pragma unroll
    for (int kblk = 0; kblk < 4; ++kblk){
      int row0 = q;
      bf16x8 vf0 = *(const bf16x8*)&Vtc[row0 * 64 + (((kblk * 2 + hi) ^ (row0 & 7)) * 8)];
      ctx[0][0] = __builtin_amdgcn_mfma_f32_32x32x16_bf16(vf0, pb[0][kblk], ctx[0][0], 0, 0, 0);
      ctx[1][0] = __builtin_amdgcn_mfma_f32_32x32x16_bf16(vf0, pb[1][kblk], ctx[1][0], 0, 0, 0);
      int row1 = 32 + q;
      bf16x8 vf1 = *(const bf16x8*)&Vtc[row1 * 64 + (((kblk * 2 + hi) ^ (row1 & 7)) * 8)];
      ctx[0][1] = __builtin_amdgcn_mfma_f32_32x32x16_bf16(vf1, pb[0][kblk], ctx[0][1], 0, 0, 0);
      ctx[1][1] = __builtin_amdgcn_mfma_f32_32x32x16_bf16(vf1, pb[1][kblk], ctx[1][1], 0, 0, 0);
    }
    __builtin_amdgcn_s_setprio(0);
  }

  if (NSPLIT == 1){
#pragma unroll
    for (int h = 0; h < 2; ++h){
      float invl = 1.0f / l_run[h];
      float* orow = out + (size_t)(b * 4096 + q0 + h * 32 + q) * 512 + head * 64;
#pragma unroll
      for (int g = 0; g < 4; ++g){
        float4 o0, o1;
        o0.x = ctx[h][0][4 * g + 0] * invl; o0.y = ctx[h][0][4 * g + 1] * invl;
        o0.z = ctx[h][0][4 * g + 2] * invl; o0.w = ctx[h][0][4 * g + 3] * invl;
        *(float4*)&orow[8 * g + 4 * hi] = o0;
        o1.x = ctx[h][1][4 * g + 0] * invl; o1.y = ctx[h][1][4 * g + 1] * invl;
        o1.z = ctx[h][1][4 * g + 2] * invl; o1.w = ctx[h][1][4 * g + 3] * invl;
        *(float4*)&orow[32 + 8 * g + 4 * hi] = o1;
      }
    }
  } else {
#pragma unroll
    for (int h = 0; h < 2; ++h){
      size_t row = (size_t)ksplit * 65536 + slice * 4096 + q0 + h * 32 + q;
      float* prow = pctx + row * 64;
#pragma unroll
      for (int g = 0; g < 4; ++g){
        float4 o0, o1;
        o0.x = ctx[h][0][4 * g + 0]; o0.y = ctx[h][0][4 * g + 1];
        o0.z = ctx[h][0][4 * g + 2]; o0.w = ctx[h][0][4 * g + 3];
        *(float4*)&prow[8 * g + 4 * hi] = o0;
        o1.x = ctx[h][1][4 * g + 0]; o1.y = ctx[h][1][4 * g + 1];
        o1.z = ctx[h][1][4 * g + 2]; o1.w = ctx[h][1][4 * g + 3];
        *(float4*)&prow[32 + 8 * g + 4 * hi] = o1;
      }
      if (hi == 0){
        f32x2 mlv = {m_run[h], l_run[h]};
        *(f32x2*)&pml[row * 2] = mlv;
      }
    }
  }
}

// ---------------- split-K merge ----------------
__global__ __launch_bounds__(256) void k_merge(const float* __restrict__ pctx, const float* __restrict__ pml,
                                               float* __restrict__ out){
  int idx = blockIdx.x * 256 + threadIdx.x;   // 65536 rows * 16 quads
  int row = idx >> 4, dq = (idx & 15) * 4;
  f32x2 ml0 = *(const f32x2*)&pml[(size_t)row * 2];
  f32x2 ml1 = *(const f32x2*)&pml[((size_t)65536 + row) * 2];
  float ms = fmaxf(ml0[0], ml1[0]);
  float w0 = ex2((ml0[0] - ms) * LOG2E);
  float w1 = ex2((ml1[0] - ms) * LOG2E);
  float rdenom = 1.0f / (w0 * ml0[1] + w1 * ml1[1]);
  float4 c0 = *(const float4*)&pctx[(size_t)row * 64 + dq];
  float4 c1 = *(const float4*)&pctx[((size_t)65536 + row) * 64 + dq];
  float4 o;
  o.x = (w0 * c0.x + w1 * c1.x) * rdenom;
  o.y = (w0 * c0.y + w1 * c1.y) * rdenom;
  o.z = (w0 * c0.z + w1 * c1.z) * rdenom;
  o.w = (w0 * c0.w + w1 * c1.w) * rdenom;
  int slice = row >> 12, s = row & 4095;
  int b = slice >> 3, head = slice & 7;
  *(float4*)&out[(size_t)(b * 4096 + s) * 512 + head * 64 + dq] = o;
}

extern "C" void kernel_launch(void* const* d_in, const int* in_sizes, int n_in,
                              void* d_out, int out_size, void* d_ws, size_t ws_size,
                              hipStream_t stream) {
  const float* hidden = (const float*)d_in[0];
  const float* mask   = (const float*)d_in[1];
  const float* Wq = (const float*)d_in[2];
  const float* bq = (const float*)d_in[3];
  const float* Wk = (const float*)d_in[4];
  const float* bk = (const float*)d_in[5];
  const float* Wv = (const float*)d_in[6];
  const float* bv = (const float*)d_in[7];
  float* out = (float*)d_out;
  char* ws = (char*)d_ws;

  u16* hb    = (u16*)(ws + 0x00000000);   // 8192x512 bf16      (8 MiB)
  u16* wt    = (u16*)(ws + 0x00900000);   // 1536x512 bf16      (1.5 MiB)
  float* bc  = (float*)(ws + 0x00B00000); // 1536 f32
  float* cs  = (float*)(ws + 0x00B10000); // 4096x64x2 f32      (2 MiB)
  u16* qws   = (u16*)(ws + 0x00E00000);   // 16x4096x64 bf16    (8 MiB)
  u16* kws   = (u16*)(ws + 0x01600000);   // 16x4096x64 bf16
  u16* vtws  = (u16*)(ws + 0x01E00000);   // 16x64x4096 bf16
  float* pctx= (float*)(ws + 0x02600000); // 2x65536x64 f32     (32 MiB)
  float* pml = (float*)(ws + 0x04600000); // 2x65536x2 f32      (1 MiB)

  bool split = ws_size >= 0x04700000ull;

  k_cast_hidden<<<dim3(2048), dim3(256), 0, stream>>>(hidden, hb, (2 * 4096 * 512) / 4);
  k_rope<<<dim3(512), dim3(256), 0, stream>>>(cs);
  k_prep_w<<<dim3(192), dim3(256), 0, stream>>>(Wq, Wk, Wv, bq, bk, bv, wt, bc);
  k_proj<<<dim3(64, 12), dim3(256), 0, stream>>>(hb, wt, bc, cs, qws, kws, vtws);
  if (split){
    k_attn<2><<<dim3(512), dim3(256), 0, stream>>>(qws, kws, vtws, mask, out, pctx, pml);
    k_merge<<<dim3(4096), dim3(256), 0, stream>>>(pctx, pml, out);
  } else {
    k_attn<1><<<dim3(256), dim3(256), 0, stream>>>(qws, kws, vtws, mask, out, pctx, pml);
  }
}

// Round 6
// 151.601 us; speedup vs baseline: 2.0746x; 1.0182x over previous
//
#include <hip/hip_runtime.h>
#include <hip/hip_bf16.h>
#include <math.h>

typedef __bf16 bf16_t;
typedef bf16_t bf16x8 __attribute__((ext_vector_type(8)));
typedef bf16_t bf16x2 __attribute__((ext_vector_type(2)));
typedef float f32x2 __attribute__((ext_vector_type(2)));
typedef float f32x4 __attribute__((ext_vector_type(4)));
typedef float f32x16 __attribute__((ext_vector_type(16)));
typedef unsigned short u16;
typedef unsigned int u32;
typedef u32 u32x2 __attribute__((ext_vector_type(2)));
typedef u32 u32x4 __attribute__((ext_vector_type(4)));

#define AS1 __attribute__((address_space(1)))
#define AS3 __attribute__((address_space(3)))

#define LOG2E 1.4426950408889634f

static __device__ __forceinline__ void gll16(const void* g, void* l){
  __builtin_amdgcn_global_load_lds((const AS1 u32*)g, (AS3 u32*)l, 16, 0, 0);
}

static __device__ __forceinline__ u16 f2bf(float f){
  u32 u = __builtin_bit_cast(u32, f);
  u = u + 0x7FFFu + ((u >> 16) & 1u);
  return (u16)(u >> 16);
}

static __device__ __forceinline__ u32 pk2(float a, float b){
  f32x2 v = {a, b};
  bf16x2 w = __builtin_convertvector(v, bf16x2);
  return __builtin_bit_cast(u32, w);
}

static __device__ __forceinline__ float ex2(float x){
#if __has_builtin(__builtin_amdgcn_exp2f)
  return __builtin_amdgcn_exp2f(x);
#else
  return __expf(0.6931471805599453f * x);
#endif
}

// exchange halves across lane<32 / lane>=32
static __device__ __forceinline__ void swap32(u32& a, u32& b, int hi){
#if __has_builtin(__builtin_amdgcn_permlane32_swap)
  auto r = __builtin_amdgcn_permlane32_swap((int)a, (int)b, false, false);
  a = (u32)r[0];
  b = (u32)r[1];
#else
  u32 xa = (u32)__shfl_xor((int)a, 32);
  u32 xb = (u32)__shfl_xor((int)b, 32);
  u32 na = hi ? xb : a;
  u32 nb = hi ? b : xa;
  a = na; b = nb;
#endif
}

// ---------------- prep: cast hidden fp32 -> bf16 ----------------
__global__ void k_cast_hidden(const float* __restrict__ h, u16* __restrict__ hb, int n4){
  int i = blockIdx.x * blockDim.x + threadIdx.x;
  int stride = gridDim.x * blockDim.x;
  for (; i < n4; i += stride){
    float4 v = ((const float4*)h)[i];
    ushort4 o;
    o.x = f2bf(v.x); o.y = f2bf(v.y); o.z = f2bf(v.z); o.w = f2bf(v.w);
    ((ushort4*)hb)[i] = o;
  }
}

// ---------------- prep: RoPE {cos,sin} pair table [4096][64] ----------------
__global__ __launch_bounds__(256) void k_rope(float* __restrict__ cs){
  int idx = blockIdx.x * 256 + threadIdx.x;   // 4096 * 32
  int s = idx >> 5, i = idx & 31;
  double invf = 1.0 / pow(10000.0, (double)(2 * i) / 64.0);
  float ang = (float)s * (float)invf;
  float sn, cv;
  sincosf(ang, &sn, &cv);
  f32x4 v = {cv, sn, cv, sn};                 // duplicate pair (repeat_interleave)
  *(f32x4*)&cs[(size_t)s * 128 + i * 4] = v;
}

// ---------------- prep: W^T concat via LDS tiles (coalesced both sides) ----------------
__global__ __launch_bounds__(256) void k_prep_w(const float* __restrict__ Wq, const float* __restrict__ Wk,
                         const float* __restrict__ Wv, const float* __restrict__ bq,
                         const float* __restrict__ bk, const float* __restrict__ bv,
                         u16* __restrict__ wt, float* __restrict__ bc){
  __shared__ float T[64][65];
  int blk = blockIdx.x;
  int t = blk >> 6, rem = blk & 63;
  int tj = rem >> 3, tk = rem & 7;
  int j0 = tj * 64, k0 = tk * 64;
  const float* W = (t == 0) ? Wq : (t == 1 ? Wk : Wv);
  int tid = threadIdx.x;

#pragma unroll
  for (int it = 0; it < 4; ++it){
    int idx = it * 256 + tid;
    int r = idx >> 4, c4 = idx & 15;
    float4 v = *(const float4*)&W[(size_t)(k0 + r) * 512 + j0 + c4 * 4];
    T[r][c4 * 4 + 0] = v.x; T[r][c4 * 4 + 1] = v.y;
    T[r][c4 * 4 + 2] = v.z; T[r][c4 * 4 + 3] = v.w;
  }
  __syncthreads();

#pragma unroll
  for (int it = 0; it < 2; ++it){
    int idx = it * 256 + tid;
    int rr = idx >> 3, g8 = idx & 7;
    u32x4 wv;
#pragma unroll
    for (int e = 0; e < 4; ++e)
      wv[e] = pk2(T[g8 * 8 + 2 * e][rr], T[g8 * 8 + 2 * e + 1][rr]);
    *(u32x4*)&wt[(size_t)(t * 512 + j0 + rr) * 512 + k0 + g8 * 8] = wv;
  }

  int gi = blk * 256 + tid;
  if (gi < 1536){
    int tt = gi >> 9, jj = gi & 511;
    const float* bsrc = (tt == 0) ? bq : (tt == 1 ? bk : bv);
    bc[gi] = bsrc[jj];
  }
}

// ---------------- fused QKV GEMM + bias + RoPE + layout ----------------
__global__ __launch_bounds__(256) void k_proj(const u16* __restrict__ hb, const u16* __restrict__ wt,
                      const float* __restrict__ bc, const float* __restrict__ cs,
                      u16* __restrict__ qws, u16* __restrict__ kws, u16* __restrict__ vt){
  __shared__ __align__(16) u16 SH[2][128 * 64];
  u16* At = SH[0];
  u16* Bt = SH[1];
  int tid = threadIdx.x;
  int lane = tid & 63;
  int c = lane & 15, g = lane >> 4;
  int wave = tid >> 6;
  int wm = wave >> 1, wn = wave & 1;
  int m0 = blockIdx.x * 128;
  int n0 = blockIdx.y * 128;

  const f32x4 vzero = {0.f, 0.f, 0.f, 0.f};
  f32x4 acc[4][4];
#pragma unroll
  for (int a = 0; a < 4; ++a)
#pragma unroll
    for (int b2 = 0; b2 < 4; ++b2) acc[a][b2] = vzero;

  for (int kc = 0; kc < 512; kc += 64){
    __syncthreads();
#pragma unroll
    for (int it = 0; it < 4; ++it){
      int j16 = it * 256 + tid;
      int row = j16 >> 3, u = j16 & 7;
      int us = u ^ (row & 7);
      gll16(hb + (size_t)(m0 + row) * 512 + kc + us * 8, &At[j16 * 8]);
      gll16(wt + (size_t)(n0 + row) * 512 + kc + us * 8, &Bt[j16 * 8]);
    }
    __syncthreads();
#pragma unroll
    for (int ch = 0; ch < 2; ++ch){
      bf16x8 af[4], bfg[4];
#pragma unroll
      for (int mt = 0; mt < 4; ++mt){
        int r = wm * 64 + mt * 16 + c;
        af[mt] = *(const bf16x8*)&At[r * 64 + ((g + 4 * ch) ^ (r & 7)) * 8];
      }
#pragma unroll
      for (int nt = 0; nt < 4; ++nt){
        int r = wn * 64 + nt * 16 + c;
        bfg[nt] = *(const bf16x8*)&Bt[r * 64 + ((g + 4 * ch) ^ (r & 7)) * 8];
      }
#pragma unroll
      for (int mt = 0; mt < 4; ++mt)
#pragma unroll
        for (int nt = 0; nt < 4; ++nt)
          acc[mt][nt] = __builtin_amdgcn_mfma_f32_16x16x32_bf16(af[mt], bfg[nt], acc[mt][nt], 0, 0, 0);
    }
  }

  int colbase = n0 + wn * 64;
  int typ = colbase >> 9;                     // 0=q 1=k 2=v (block-uniform)
  int head = (colbase >> 6) & 7;
  int rowbase = m0 + wm * 64;
  int bb = rowbase >> 12, s0 = rowbase & 4095;
  float bias[4];
#pragma unroll
  for (int nt = 0; nt < 4; ++nt) bias[nt] = bc[colbase + nt * 16 + c];

  if (typ == 2){
    __syncthreads();
    u16* Tw = &SH[0][0] + wave * 4096;
#pragma unroll
    for (int nt = 0; nt < 4; ++nt){
      int n = nt * 16 + c;
#pragma unroll
      for (int mt = 0; mt < 4; ++mt){
        float a0 = acc[mt][nt][0] + bias[nt];
        float a1 = acc[mt][nt][1] + bias[nt];
        float a2 = acc[mt][nt][2] + bias[nt];
        float a3 = acc[mt][nt][3] + bias[nt];
        int p = (mt * 4 + g) ^ (c & 14);
        u32x2 wv = { pk2(a0, a1), pk2(a2, a3) };
        *(u32x2*)&Tw[n * 64 + p * 4] = wv;
      }
    }
    __syncthreads();
    size_t vbase = (size_t)(bb * 8 + head) * 64 * 4096;
#pragma unroll
    for (int pass = 0; pass < 8; ++pass){
      int n = pass * 8 + (lane >> 3);
      int lu = (lane & 7) * 2;
      int p = lu ^ (n & 14);
      u32x4 vv = *(const u32x4*)&Tw[n * 64 + p * 4];
      *(u32x4*)&vt[vbase + (size_t)n * 4096 + s0 + (lane & 7) * 8] = vv;
    }
  } else {
    u16* dst = (typ == 0) ? qws : kws;
    float scale = (typ == 0) ? 0.125f : 1.0f;
#pragma unroll
    for (int mt = 0; mt < 4; ++mt){
#pragma unroll
      for (int reg = 0; reg < 4; ++reg){
        int m = rowbase + mt * 16 + g * 4 + reg;
        int b = m >> 12, s = m & 4095;
        const f32x2* cs_s = (const f32x2*)(cs + (size_t)s * 128);
        size_t base = ((size_t)(b * 8 + head) * 4096 + s) * 64;
#pragma unroll
        for (int nt = 0; nt < 4; ++nt){
          int nn = nt * 16 + c;
          float y = acc[mt][nt][reg] + bias[nt];
          f32x2 p2 = cs_s[nn];
          float rot;
          if (nn < 32){
            rot = -(acc[mt][nt + 2][reg] + bias[nt + 2]);
          } else {
            rot = acc[mt][nt - 2][reg] + bias[nt - 2];
          }
          float o = (y * p2[0] + rot * p2[1]) * scale;
          dst[base + nn] = f2bf(o);
        }
      }
    }
  }
}

// ---------------- flash attention: 4 waves x 64q, 32x32x16 MFMA, in-register softmax ----------------
// Mask folded into QK accumulator init; l computed by ones-row MFMA (matrix pipe).
template<int NSPLIT>
__global__ __launch_bounds__(256, 2) void k_attn(const u16* __restrict__ qws, const u16* __restrict__ kws,
                      const u16* __restrict__ vtws, const float* __restrict__ mask,
                      float* __restrict__ out, float* __restrict__ pctx, float* __restrict__ pml){
  __shared__ __align__(16) u16 smem[2][2][64 * 64];

  int tid = threadIdx.x;
  int lane = tid & 63;
  int q = lane & 31, hi = lane >> 5;
  int wave = tid >> 6;

  // XCD-aware bijective swizzle (grid = 256*NSPLIT, multiple of 8)
  int cpx = (gridDim.x >> 3);
  int nbid = (blockIdx.x & 7) * cpx + (blockIdx.x >> 3);
  int slice = nbid / (16 * NSPLIT);
  int rem = nbid - slice * 16 * NSPLIT;
  int ksplit = rem >> 4;                       // 0..NSPLIT-1
  int qt = rem & 15;
  int b = slice >> 3, head = slice & 7;
  int q0 = qt * 256 + wave * 64;               // 64 q per wave
  const int NT = 64 / NSPLIT;
  int kstart = ksplit * (4096 / NSPLIT);

  const u16* qs = qws + (size_t)slice * 4096 * 64;
  const u16* ks = kws + (size_t)slice * 4096 * 64;
  const u16* vs = vtws + (size_t)slice * 64 * 4096;
  const float* mk = mask + b * 4096;

  // Q fragments for both q-halves: lane holds Q[q0 + h*32 + q][d]
  bf16x8 qf[2][4];
#pragma unroll
  for (int h = 0; h < 2; ++h){
    const u16* qrow = qs + (size_t)(q0 + h * 32 + q) * 64;
#pragma unroll
    for (int dblk = 0; dblk < 4; ++dblk)
      qf[h][dblk] = *(const bf16x8*)&qrow[dblk * 16 + hi * 8];
  }

  // ones A-fragment for the l-sum MFMA
  const u32x4 onesu = {0x3F803F80u, 0x3F803F80u, 0x3F803F80u, 0x3F803F80u};
  const bf16x8 onesf = __builtin_bit_cast(bf16x8, onesu);

  const f32x16 vz = {0.f,0.f,0.f,0.f,0.f,0.f,0.f,0.f,0.f,0.f,0.f,0.f,0.f,0.f,0.f,0.f};
  f32x16 ctx[2][2];                            // [h][dv-half]
#pragma unroll
  for (int h = 0; h < 2; ++h){ ctx[h][0] = vz; ctx[h][1] = vz; }
  f32x16 lacc[2];                              // l accumulated by MFMA; only reg[0] is used
  lacc[0] = vz; lacc[1] = vz;
  float m_run[2] = {-1e30f, -1e30f};
  float ml[2] = {-1e30f * LOG2E, -1e30f * LOG2E};

  auto stage = [&](int buf, int kc){
#pragma unroll
    for (int it = 0; it < 2; ++it){
      int j = it * 256 + tid;
      int row = j >> 3, u = j & 7;
      int us = u ^ (row & 7);
      gll16(ks + (size_t)(kc + row) * 64 + us * 8, &smem[buf][0][j * 8]);
      gll16(vs + (size_t)row * 4096 + kc + us * 8, &smem[buf][1][j * 8]);
    }
  };

  stage(0, kstart);

  for (int t = 0; t < NT; ++t){
    int kc = kstart + t * 64;
    __syncthreads();
    if (t < NT - 1) stage((t + 1) & 1, kc + 64);
    const u16* Kb  = &smem[t & 1][0][0];
    const u16* Vtc = &smem[t & 1][1][0];

    // mask loads -> QK accumulator init (C/D layout key = (r&3)+8*(r>>2)+4*hi)
    f32x16 mv[2];
#pragma unroll
    for (int kb = 0; kb < 2; ++kb)
#pragma unroll
      for (int gg = 0; gg < 4; ++gg){
        float4 m4 = *(const float4*)&mk[kc + kb * 32 + gg * 8 + hi * 4];
        mv[kb][4 * gg + 0] = m4.x; mv[kb][4 * gg + 1] = m4.y;
        mv[kb][4 * gg + 2] = m4.z; mv[kb][4 * gg + 3] = m4.w;
      }

    // QK^T (swapped): S^T[key][q] + mask, kf shared by both q-halves
    f32x16 sv[2][2];                            // [h][kb]
    __builtin_amdgcn_s_setprio(1);
#pragma unroll
    for (int kb = 0; kb < 2; ++kb){
      f32x16 a0 = mv[kb], a1 = mv[kb];
#pragma unroll
      for (int dblk = 0; dblk < 4; ++dblk){
        int row = kb * 32 + q;
        bf16x8 kf = *(const bf16x8*)&Kb[row * 64 + (((dblk * 2 + hi) ^ (row & 7)) * 8)];
        a0 = __builtin_amdgcn_mfma_f32_32x32x16_bf16(kf, qf[0][dblk], a0, 0, 0, 0);
        a1 = __builtin_amdgcn_mfma_f32_32x32x16_bf16(kf, qf[1][dblk], a1, 0, 0, 0);
      }
      sv[0][kb] = a0;
      sv[1][kb] = a1;
    }
    __builtin_amdgcn_s_setprio(0);

#pragma unroll
    for (int h = 0; h < 2; ++h){
      // tile max: max3-shaped triple tree over 32 values
#define SVV(j) sv[h][(j) >> 4][(j) & 15]
      float tr[11];
#pragma unroll
      for (int i = 0; i < 10; ++i)
        tr[i] = fmaxf(fmaxf(SVV(3 * i), SVV(3 * i + 1)), SVV(3 * i + 2));
      tr[10] = fmaxf(SVV(30), SVV(31));
#undef SVV
      float u0 = fmaxf(fmaxf(tr[0], tr[1]), tr[2]);
      float u1 = fmaxf(fmaxf(tr[3], tr[4]), tr[5]);
      float u2 = fmaxf(fmaxf(tr[6], tr[7]), tr[8]);
      float u3 = fmaxf(tr[9], tr[10]);
      float pmax = fmaxf(fmaxf(fmaxf(u0, u1), u2), u3);
      pmax = fmaxf(pmax, __shfl_xor(pmax, 32));

      // defer-max (T13)
      if (__any(pmax > m_run[h] + 8.f)){
        float mnew = fmaxf(m_run[h], pmax);
        float al = ex2((m_run[h] - mnew) * LOG2E);
        m_run[h] = mnew;
        ml[h] = mnew * LOG2E;
        lacc[h][0] *= al;
#pragma unroll
        for (int r = 0; r < 16; ++r){ ctx[h][0][r] *= al; ctx[h][1][r] *= al; }
      }

      // p = exp2(s*log2e - ml); sum comes from the ones-MFMA below
#pragma unroll
      for (int kb = 0; kb < 2; ++kb)
#pragma unroll
        for (int r = 0; r < 16; ++r)
          sv[h][kb][r] = ex2(fmaf(sv[h][kb][r], LOG2E, -ml[h]));
    }

    // pack P and assemble PV B-frags per q-half
    bf16x8 pb[2][4];
#pragma unroll
    for (int h = 0; h < 2; ++h){
      u32 W0[2][4], W1[2][4];
#pragma unroll
      for (int kb = 0; kb < 2; ++kb)
#pragma unroll
        for (int g = 0; g < 4; ++g){
          W0[kb][g] = pk2(sv[h][kb][4 * g + 0], sv[h][kb][4 * g + 1]);
          W1[kb][g] = pk2(sv[h][kb][4 * g + 2], sv[h][kb][4 * g + 3]);
        }
#pragma unroll
      for (int kblk = 0; kblk < 4; ++kblk){
        int kb = kblk >> 1, j = kblk & 1;
        u32 w0 = W0[kb][2 * j + 0], w2 = W0[kb][2 * j + 1];
        u32 w1 = W1[kb][2 * j + 0], w3 = W1[kb][2 * j + 1];
        swap32(w0, w2, hi);
        swap32(w1, w3, hi);
        u32x4 wv = {w0, w1, w2, w3};
        pb[h][kblk] = __builtin_bit_cast(bf16x8, wv);
      }
    }

    // PV: O^T[dv][q] += V^T[dv][key] * P^T[key][q]; plus l-sum via ones-row MFMA
    __builtin_amdgcn_s_setprio(1);
#pragma unroll
    for (int kblk = 0; kblk < 4; ++kblk){
      int row0 = q;
      bf16x8 vf0 = *(const bf16x8*)&Vtc[row0 * 64 + (((kblk * 2 + hi) ^ (row0 & 7)) * 8)];
      ctx[0][0] = __builtin_amdgcn_mfma_f32_32x32x16_bf16(vf0, pb[0][kblk], ctx[0][0], 0, 0, 0);
      ctx[1][0] = __builtin_amdgcn_mfma_f32_32x32x16_bf16(vf0, pb[1][kblk], ctx[1][0], 0, 0, 0);
      int row1 = 32 + q;
      bf16x8 vf1 = *(const bf16x8*)&Vtc[row1 * 64 + (((kblk * 2 + hi) ^ (row1 & 7)) * 8)];
      ctx[0][1] = __builtin_amdgcn_mfma_f32_32x32x16_bf16(vf1, pb[0][kblk], ctx[0][1], 0, 0, 0);
      ctx[1][1] = __builtin_amdgcn_mfma_f32_32x32x16_bf16(vf1, pb[1][kblk], ctx[1][1], 0, 0, 0);
      lacc[0] = __builtin_amdgcn_mfma_f32_32x32x16_bf16(onesf, pb[0][kblk], lacc[0], 0, 0, 0);
      lacc[1] = __builtin_amdgcn_mfma_f32_32x32x16_bf16(onesf, pb[1][kblk], lacc[1], 0, 0, 0);
    }
    __builtin_amdgcn_s_setprio(0);
  }

  if (NSPLIT == 1){
#pragma unroll
    for (int h = 0; h < 2; ++h){
      float invl = 1.0f / lacc[h][0];
      float* orow = out + (size_t)(b * 4096 + q0 + h * 32 + q) * 512 + head * 64;
#pragma unroll
      for (int g = 0; g < 4; ++g){
        float4 o0, o1;
        o0.x = ctx[h][0][4 * g + 0] * invl; o0.y = ctx[h][0][4 * g + 1] * invl;
        o0.z = ctx[h][0][4 * g + 2] * invl; o0.w = ctx[h][0][4 * g + 3] * invl;
        *(float4*)&orow[8 * g + 4 * hi] = o0;
        o1.x = ctx[h][1][4 * g + 0] * invl; o1.y = ctx[h][1][4 * g + 1] * invl;
        o1.z = ctx[h][1][4 * g + 2] * invl; o1.w = ctx[h][1][4 * g + 3] * invl;
        *(float4*)&orow[32 + 8 * g + 4 * hi] = o1;
      }
    }
  } else {
#pragma unroll
    for (int h = 0; h < 2; ++h){
      size_t row = (size_t)ksplit * 65536 + slice * 4096 + q0 + h * 32 + q;
      float* prow = pctx + row * 64;
#pragma unroll
      for (int g = 0; g < 4; ++g){
        float4 o0, o1;
        o0.x = ctx[h][0][4 * g + 0]; o0.y = ctx[h][0][4 * g + 1];
        o0.z = ctx[h][0][4 * g + 2]; o0.w = ctx[h][0][4 * g + 3];
        *(float4*)&prow[8 * g + 4 * hi] = o0;
        o1.x = ctx[h][1][4 * g + 0]; o1.y = ctx[h][1][4 * g + 1];
        o1.z = ctx[h][1][4 * g + 2]; o1.w = ctx[h][1][4 * g + 3];
        *(float4*)&prow[32 + 8 * g + 4 * hi] = o1;
      }
      if (hi == 0){
        f32x2 mlv = {m_run[h], lacc[h][0]};
        *(f32x2*)&pml[row * 2] = mlv;
      }
    }
  }
}

// ---------------- split-K merge ----------------
__global__ __launch_bounds__(256) void k_merge(const float* __restrict__ pctx, const float* __restrict__ pml,
                                               float* __restrict__ out){
  int idx = blockIdx.x * 256 + threadIdx.x;   // 65536 rows * 16 quads
  int row = idx >> 4, dq = (idx & 15) * 4;
  f32x2 ml0 = *(const f32x2*)&pml[(size_t)row * 2];
  f32x2 ml1 = *(const f32x2*)&pml[((size_t)65536 + row) * 2];
  float ms = fmaxf(ml0[0], ml1[0]);
  float w0 = ex2((ml0[0] - ms) * LOG2E);
  float w1 = ex2((ml1[0] - ms) * LOG2E);
  float rdenom = 1.0f / (w0 * ml0[1] + w1 * ml1[1]);
  float4 c0 = *(const float4*)&pctx[(size_t)row * 64 + dq];
  float4 c1 = *(const float4*)&pctx[((size_t)65536 + row) * 64 + dq];
  float4 o;
  o.x = (w0 * c0.x + w1 * c1.x) * rdenom;
  o.y = (w0 * c0.y + w1 * c1.y) * rdenom;
  o.z = (w0 * c0.z + w1 * c1.z) * rdenom;
  o.w = (w0 * c0.w + w1 * c1.w) * rdenom;
  int slice = row >> 12, s = row & 4095;
  int b = slice >> 3, head = slice & 7;
  *(float4*)&out[(size_t)(b * 4096 + s) * 512 + head * 64 + dq] = o;
}

extern "C" void kernel_launch(void* const* d_in, const int* in_sizes, int n_in,
                              void* d_out, int out_size, void* d_ws, size_t ws_size,
                              hipStream_t stream) {
  const float* hidden = (const float*)d_in[0];
  const float* mask   = (const float*)d_in[1];
  const float* Wq = (const float*)d_in[2];
  const float* bq = (const float*)d_in[3];
  const float* Wk = (const float*)d_in[4];
  const float* bk = (const float*)d_in[5];
  const float* Wv = (const float*)d_in[6];
  const float* bv = (const float*)d_in[7];
  float* out = (float*)d_out;
  char* ws = (char*)d_ws;

  u16* hb    = (u16*)(ws + 0x00000000);   // 8192x512 bf16      (8 MiB)
  u16* wt    = (u16*)(ws + 0x00900000);   // 1536x512 bf16      (1.5 MiB)
  float* bc  = (float*)(ws + 0x00B00000); // 1536 f32
  float* cs  = (float*)(ws + 0x00B10000); // 4096x64x2 f32      (2 MiB)
  u16* qws   = (u16*)(ws + 0x00E00000);   // 16x4096x64 bf16    (8 MiB)
  u16* kws   = (u16*)(ws + 0x01600000);   // 16x4096x64 bf16
  u16* vtws  = (u16*)(ws + 0x01E00000);   // 16x64x4096 bf16
  float* pctx= (float*)(ws + 0x02600000); // 2x65536x64 f32     (32 MiB)
  float* pml = (float*)(ws + 0x04600000); // 2x65536x2 f32      (1 MiB)

  bool split = ws_size >= 0x04700000ull;

  k_cast_hidden<<<dim3(2048), dim3(256), 0, stream>>>(hidden, hb, (2 * 4096 * 512) / 4);
  k_rope<<<dim3(512), dim3(256), 0, stream>>>(cs);
  k_prep_w<<<dim3(192), dim3(256), 0, stream>>>(Wq, Wk, Wv, bq, bk, bv, wt, bc);
  k_proj<<<dim3(64, 12), dim3(256), 0, stream>>>(hb, wt, bc, cs, qws, kws, vtws);
  if (split){
    k_attn<2><<<dim3(512), dim3(256), 0, stream>>>(qws, kws, vtws, mask, out, pctx, pml);
    k_merge<<<dim3(4096), dim3(256), 0, stream>>>(pctx, pml, out);
  } else {
    k_attn<1><<<dim3(256), dim3(256), 0, stream>>>(qws, kws, vtws, mask, out, pctx, pml);
  }
}